// Round 11
// baseline (201.547 us; speedup 1.0000x reference)
//
#include <hip/hip_runtime.h>
#include <hip/hip_fp16.h>
#include <math.h>

#define NN 50000
#define EE 800000
#define FIN 128
#define F1  128   // HEADS*HID
#define NH  8
#define DH  16
#define F2  32
#define SLOPE 0.2f
#define LOG2E 1.44269504f

#define EB 4096                    // edges per split block
#define NBLK ((EE + EB - 1) / EB)  // 196
#define BK  391                    // coarse buckets = ceil(NN/128)
#define SEGCAP 4096                // max edges per bucket segment (mean ~2046)
#define PREPB 80                   // prep blocks: (128*128 + 32*128)/256
#define GEMM1B ((NN + 63) / 64)    // 782

typedef _Float16 f16x8 __attribute__((ext_vector_type(8)));
typedef float    f32x4 __attribute__((ext_vector_type(4)));

// ================= k1: [hist | prep] fused =================
__global__ __launch_bounds__(256) void k1_hist_prep(const int* __restrict__ dst,
        const float* __restrict__ W1, const float* __restrict__ W2,
        __half* __restrict__ wt1, __half* __restrict__ wt2, int* __restrict__ hist) {
    int tid = threadIdx.x;
    if (blockIdx.x < NBLK) {
        __shared__ int lc[BK];
        for (int i = tid; i < BK; i += 256) lc[i] = 0;
        __syncthreads();
        int base = blockIdx.x * EB;
        int end = base + EB; if (end > EE) end = EE;
        for (int i = base + tid; i < end; i += 256)
            atomicAdd(&lc[dst[i] >> 7], 1);
        __syncthreads();
        for (int i = tid; i < BK; i += 256)
            if (lc[i]) atomicAdd(&hist[i], lc[i]);
    } else {
        int gidx = (blockIdx.x - NBLK) * 256 + tid;
        if (gidx < FIN * F1) {
            int n = gidx >> 7, k = gidx & 127;
            wt1[gidx] = __float2half(W1[k * F1 + n]);
        } else {
            int t2 = gidx - FIN * F1;
            if (t2 < F2 * FIN) {
                int n = t2 >> 7, k = t2 & 127;
                wt2[t2] = __float2half(W2[k * F2 + n]);
            }
        }
    }
}

// ================= k2: [split | gemm1] fused (dynamic LDS 52224 B) =================
// blocks 0..NBLK-1: multisplit (re-derives hist prefix locally; cursor zero-based)
// blocks NBLK..NBLK+GEMM1B-1: MFMA fp16 GEMM1 + fp32 es/ed epilogue
extern __shared__ char smem_k2[];
__global__ __launch_bounds__(256) void k2_split_gemm1(const int* __restrict__ src,
        const int* __restrict__ dst, const int* __restrict__ hist, int* __restrict__ cursor,
        unsigned int* __restrict__ sorted,
        const float* __restrict__ h, const __half* __restrict__ wt1,
        const float* __restrict__ a1s, const float* __restrict__ a1d,
        __half* __restrict__ z1h, float* __restrict__ es1x, float* __restrict__ ed1x) {
    int tid = threadIdx.x;
    if (blockIdx.x < NBLK) {
        unsigned int*   recs = (unsigned int*)smem_k2;              // 16384 B
        unsigned short* rbk  = (unsigned short*)(smem_k2 + 16384);  // 8192 B
        int* lc    = (int*)(smem_k2 + 24576);                       // 2048 B
        int* lofs  = (int*)(smem_k2 + 26624);                       // 2048 B
        int* lcur  = (int*)(smem_k2 + 28672);                       // 2048 B
        int* delta = (int*)(smem_k2 + 30720);                       // 2048 B
        int* bscan = (int*)(smem_k2 + 32768);                       // 2048 B
        int* sh    = (int*)(smem_k2 + 34816);                       // 1024 B
        for (int i = tid; i < 512; i += 256) lc[i] = 0;
        __syncthreads();
        int base = blockIdx.x * EB;
        int cnt = EE - base; if (cnt > EB) cnt = EB;
        unsigned int myrec[16];
        #pragma unroll
        for (int k = 0; k < 16; ++k) {
            int i = base + tid + k * 256;
            myrec[k] = 0xFFFFFFFFu;
            if (i - base < cnt) {
                unsigned int d = (unsigned int)dst[i];
                myrec[k] = (d << 16) | (unsigned int)src[i];
                atomicAdd(&lc[d >> 7], 1);
            }
        }
        __syncthreads();
        // scan lc -> lofs
        int a0 = lc[2 * tid], a1 = lc[2 * tid + 1];
        int tsum = a0 + a1;
        sh[tid] = tsum;
        __syncthreads();
        for (int off = 1; off < 256; off <<= 1) {
            int t = (tid >= off) ? sh[tid - off] : 0;
            __syncthreads(); sh[tid] += t; __syncthreads();
        }
        int ex = sh[tid] - tsum;
        lofs[2 * tid] = ex;
        lofs[2 * tid + 1] = ex + a0;
        __syncthreads();
        // scan hist -> bscan (global bucket bases)
        int h0 = hist[2 * tid], h1 = hist[2 * tid + 1];
        int hsum = h0 + h1;
        sh[tid] = hsum;
        __syncthreads();
        for (int off = 1; off < 256; off <<= 1) {
            int t = (tid >= off) ? sh[tid - off] : 0;
            __syncthreads(); sh[tid] += t; __syncthreads();
        }
        int hex = sh[tid] - hsum;
        bscan[2 * tid] = hex;
        bscan[2 * tid + 1] = hex + h0;
        __syncthreads();
        for (int b = tid; b < BK; b += 256) {
            int c = lc[b];
            lcur[b] = lofs[b];
            if (c) {
                int g = atomicAdd(&cursor[b], c);    // cursor zero-initialized
                delta[b] = bscan[b] + g - lofs[b];
            }
        }
        __syncthreads();
        #pragma unroll
        for (int k = 0; k < 16; ++k) {
            if (myrec[k] != 0xFFFFFFFFu) {
                int b = (int)(myrec[k] >> 23);      // dst >> 7
                int pos = atomicAdd(&lcur[b], 1);
                recs[pos] = myrec[k];
                rbk[pos] = (unsigned short)b;
            }
        }
        __syncthreads();
        for (int s = tid; s < cnt; s += 256)
            sorted[s + delta[rbk[s]]] = recs[s];
    } else {
        __half* hs  = (__half*)smem_k2;              // 64*136 = 17408 B
        __half* wls = (__half*)(smem_k2 + 17408);    // 128*136 = 34816 B
        // stage W1^T fp16 via b128 copies (pre-transposed)
        for (int c = tid; c < 2048; c += 256) {
            int row = c >> 4, ch = c & 15;
            *(float4*)&wls[row * 136 + ch * 8] = *(const float4*)&wt1[row * 128 + ch * 8];
        }
        int rowBase = (blockIdx.x - NBLK) * 64;
        for (int idx4 = tid; idx4 < 64 * 32; idx4 += 256) {
            int r = idx4 >> 5, cc = (idx4 & 31) * 4;
            int n = rowBase + r;
            float4 v = (n < NN) ? *(const float4*)&h[(size_t)n * FIN + cc] : make_float4(0, 0, 0, 0);
            union { __half2 h2[2]; int2 i; } u;
            u.h2[0] = __floats2half2_rn(v.x, v.y);
            u.h2[1] = __floats2half2_rn(v.z, v.w);
            *(int2*)&hs[r * 136 + cc] = u.i;
        }
        __syncthreads();
        int l = tid & 63, w = tid >> 6;
        int q = l >> 4, cl = l & 15;
        int m0 = w * 16;
        float as[8], ad[8];
        #pragma unroll
        for (int t = 0; t < 8; ++t) { as[t] = a1s[t * DH + cl]; ad[t] = a1d[t * DH + cl]; }
        f32x4 acc[8];
        #pragma unroll
        for (int t = 0; t < 8; ++t) acc[t] = (f32x4){0.f, 0.f, 0.f, 0.f};
        const __half* ap = &hs[(m0 + cl) * 136 + q * 8];
        const __half* bp = &wls[cl * 136 + q * 8];
        #pragma unroll
        for (int k0 = 0; k0 < 128; k0 += 32) {
            f16x8 af = *(const f16x8*)(ap + k0);
            #pragma unroll
            for (int t = 0; t < 8; ++t) {
                f16x8 bf = *(const f16x8*)(bp + t * 16 * 136 + k0);
                acc[t] = __builtin_amdgcn_mfma_f32_16x16x32_f16(af, bf, acc[t], 0, 0, 0);
            }
        }
        #pragma unroll
        for (int t = 0; t < 8; ++t) {
            #pragma unroll
            for (int reg = 0; reg < 4; ++reg) {
                int row = rowBase + m0 + q * 4 + reg;
                float z = acc[t][reg];
                float s = z * as[t], d = z * ad[t];
                s += __shfl_xor(s, 1, 64); d += __shfl_xor(d, 1, 64);
                s += __shfl_xor(s, 2, 64); d += __shfl_xor(d, 2, 64);
                s += __shfl_xor(s, 4, 64); d += __shfl_xor(d, 4, 64);
                s += __shfl_xor(s, 8, 64); d += __shfl_xor(d, 8, 64);
                if (row < NN) {
                    z1h[(size_t)row * F1 + t * 16 + cl] = __float2half(z);
                    if (cl == 0) {
                        es1x[row * NH + t] = s * LOG2E;
                        ed1x[row * NH + t] = d * LOG2E;
                    }
                }
            }
        }
    }
}

// ================= S4: per-bucket dense CSR build (local hist scan) =================
__global__ __launch_bounds__(256) void csrbuild_kernel(const int* __restrict__ hist,
        const unsigned int* __restrict__ sorted, unsigned short* __restrict__ csr,
        int* __restrict__ row_ptr) {
    __shared__ unsigned int recs[SEGCAP];     // 16 KB
    __shared__ unsigned short csr_sh[SEGCAP]; // 8 KB
    __shared__ int ncnt[128], ncur[128];
    __shared__ int sh[256];
    __shared__ int bscan[512];
    int b = blockIdx.x;
    int tid = threadIdx.x;
    // scan hist -> bscan
    int h0 = hist[2 * tid], h1 = hist[2 * tid + 1];
    int hsum = h0 + h1;
    sh[tid] = hsum;
    if (tid < 128) ncnt[tid] = 0;
    __syncthreads();
    for (int off = 1; off < 256; off <<= 1) {
        int t = (tid >= off) ? sh[tid - off] : 0;
        __syncthreads(); sh[tid] += t; __syncthreads();
    }
    int hex = sh[tid] - hsum;
    bscan[2 * tid] = hex;
    bscan[2 * tid + 1] = hex + h0;
    __syncthreads();
    int s0 = bscan[b], s1 = bscan[b + 1];     // b+1 <= 391 < 512; hist zero-padded
    int cnt = s1 - s0; if (cnt > SEGCAP) cnt = SEGCAP;
    for (int i = tid; i < cnt; i += 256) {
        unsigned int r = sorted[s0 + i];
        recs[i] = r;
        atomicAdd(&ncnt[(r >> 16) & 127], 1);
    }
    __syncthreads();
    int v = (tid < 128) ? ncnt[tid] : 0;
    sh[tid] = v;
    __syncthreads();
    for (int off = 1; off < 256; off <<= 1) {
        int t = (tid >= off) ? sh[tid - off] : 0;
        __syncthreads(); sh[tid] += t; __syncthreads();
    }
    int ex = sh[tid] - v;
    if (tid < 128) {
        ncur[tid] = ex;
        int node = b * 128 + tid;
        if (node < NN) row_ptr[node] = s0 + ex;
    }
    if (b == BK - 1 && tid == 0) row_ptr[NN] = EE;
    __syncthreads();
    for (int i = tid; i < cnt; i += 256) {
        unsigned int r = recs[i];
        int local = (r >> 16) & 127;
        int p = atomicAdd(&ncur[local], 1);
        csr_sh[p] = (unsigned short)(r & 0xFFFFu);
    }
    __syncthreads();
    for (int i = tid; i < cnt; i += 256)
        csr[s0 + i] = csr_sh[i];
}

// ================= GEMM2 (MFMA fp16) + fp32 es/ed epilogue =================
__global__ __launch_bounds__(256) void gemm2_kernel(const __half* __restrict__ h1h,
        const __half* __restrict__ wt2, const float* __restrict__ a2s, const float* __restrict__ a2d,
        __half* __restrict__ z2h, float* __restrict__ es2x, float* __restrict__ ed2x) {
    __shared__ alignas(16) __half hs[64 * 136];    // 17.4 KB
    __shared__ alignas(16) __half wls[32 * 136];   // 8.7 KB
    int tid = threadIdx.x;
    for (int c = tid; c < 512; c += 256) {
        int row = c >> 4, ch = c & 15;
        *(float4*)&wls[row * 136 + ch * 8] = *(const float4*)&wt2[row * 128 + ch * 8];
    }
    int rowBase = blockIdx.x * 64;
    for (int idx8 = tid; idx8 < 64 * 16; idx8 += 256) {
        int r = idx8 >> 4, cc = (idx8 & 15) * 8;
        int n = rowBase + r;
        float4 v = make_float4(0, 0, 0, 0);
        if (n < NN) v = *(const float4*)&h1h[(size_t)n * FIN + cc];
        *(float4*)&hs[r * 136 + cc] = v;
    }
    __syncthreads();
    int l = tid & 63, w = tid >> 6;
    int q = l >> 4, cl = l & 15;
    int m0 = w * 16;
    float as0 = a2s[cl], as1 = a2s[16 + cl];
    float ad0 = a2d[cl], ad1 = a2d[16 + cl];
    f32x4 acc[2];
    acc[0] = (f32x4){0.f, 0.f, 0.f, 0.f};
    acc[1] = (f32x4){0.f, 0.f, 0.f, 0.f};
    const __half* ap = &hs[(m0 + cl) * 136 + q * 8];
    const __half* bp = &wls[cl * 136 + q * 8];
    #pragma unroll
    for (int k0 = 0; k0 < 128; k0 += 32) {
        f16x8 af = *(const f16x8*)(ap + k0);
        #pragma unroll
        for (int t = 0; t < 2; ++t) {
            f16x8 bf = *(const f16x8*)(bp + t * 16 * 136 + k0);
            acc[t] = __builtin_amdgcn_mfma_f32_16x16x32_f16(af, bf, acc[t], 0, 0, 0);
        }
    }
    #pragma unroll
    for (int reg = 0; reg < 4; ++reg) {
        int row = rowBase + m0 + q * 4 + reg;
        float s = acc[0][reg] * as0 + acc[1][reg] * as1;
        float d = acc[0][reg] * ad0 + acc[1][reg] * ad1;
        s += __shfl_xor(s, 1, 64); d += __shfl_xor(d, 1, 64);
        s += __shfl_xor(s, 2, 64); d += __shfl_xor(d, 2, 64);
        s += __shfl_xor(s, 4, 64); d += __shfl_xor(d, 4, 64);
        s += __shfl_xor(s, 8, 64); d += __shfl_xor(d, 8, 64);
        if (row < NN) {
            z2h[(size_t)row * F2 + cl]      = __float2half(acc[0][reg]);
            z2h[(size_t)row * F2 + 16 + cl] = __float2half(acc[1][reg]);
            if (cl == 0) {
                es2x[row] = s * LOG2E;
                ed2x[row] = d * LOG2E;
            }
        }
    }
}

// ================= attention layer 1: 16 lanes/node, 8-wide unrolled =================
__global__ __launch_bounds__(256) void attn1_kernel(const int* __restrict__ row_ptr,
        const unsigned short* __restrict__ csr, const __half* __restrict__ z1h,
        const float* __restrict__ es, const float* __restrict__ ed,
        __half* __restrict__ h1h) {
    int gt = blockIdx.x * 256 + threadIdx.x;
    int n = gt >> 4;          // node
    int j = gt & 15;          // dim-group lane
    int hl = j >> 1;          // head
    if (n >= NN) return;
    int b0 = row_ptr[n];
    int cnt = row_ptr[n + 1] - b0;
    float edn = ed[n * NH + hl];
    float acc[8] = {0.f, 0.f, 0.f, 0.f, 0.f, 0.f, 0.f, 0.f};
    float ws = 0.f;
    int i = 0;
    for (; i + 8 <= cnt; i += 8) {
        int ss[8];
        #pragma unroll
        for (int u = 0; u < 8; ++u) ss[u] = csr[b0 + i + u];
        union { float4 f; __half2 h2[4]; } uu[8];
        #pragma unroll
        for (int u = 0; u < 8; ++u) uu[u].f = *(const float4*)&z1h[(size_t)ss[u] * F1 + j * 8];
        float ww[8];
        #pragma unroll
        for (int u = 0; u < 8; ++u) {
            float e = es[ss[u] * NH + hl] + edn;
            ww[u] = exp2f(e >= 0.f ? e : SLOPE * e);
            ws += ww[u];
        }
        #pragma unroll
        for (int t = 0; t < 4; ++t) {
            #pragma unroll
            for (int u = 0; u < 8; ++u) {
                float2 v = __half22float2(uu[u].h2[t]);
                acc[2*t]   = fmaf(ww[u], v.x, acc[2*t]);
                acc[2*t+1] = fmaf(ww[u], v.y, acc[2*t+1]);
            }
        }
    }
    for (; i < cnt; ++i) {
        int s = csr[b0 + i];
        float e = es[s * NH + hl] + edn;
        float wv = exp2f(e >= 0.f ? e : SLOPE * e);
        ws += wv;
        union { float4 f; __half2 h2[4]; } u;
        u.f = *(const float4*)&z1h[(size_t)s * F1 + j * 8];
        #pragma unroll
        for (int t = 0; t < 4; ++t) {
            float2 v = __half22float2(u.h2[t]);
            acc[2*t]   = fmaf(wv, v.x, acc[2*t]);
            acc[2*t+1] = fmaf(wv, v.y, acc[2*t+1]);
        }
    }
    float rs = ws > 0.f ? 1.0f / ws : 0.f;
    union { float4 f; __half2 h2[4]; } p;
    #pragma unroll
    for (int t = 0; t < 4; ++t) {
        float x0 = acc[2*t] * rs, x1 = acc[2*t+1] * rs;
        x0 = x0 > 0.f ? x0 : __expf(x0) - 1.0f;   // ELU
        x1 = x1 > 0.f ? x1 : __expf(x1) - 1.0f;
        p.h2[t] = __floats2half2_rn(x0, x1);
    }
    *(float4*)&h1h[(size_t)n * F1 + j * 8] = p.f;
}

// ================= attention layer 2: 4 lanes/node, 8-wide unrolled =================
__global__ __launch_bounds__(256) void attn2_kernel(const int* __restrict__ row_ptr,
        const unsigned short* __restrict__ csr, const __half* __restrict__ z2h,
        const float* __restrict__ es, const float* __restrict__ ed,
        float* __restrict__ out) {
    int gt = blockIdx.x * 256 + threadIdx.x;
    int n = gt >> 2;          // node
    int j = gt & 3;           // dims [8j, 8j+8)
    if (n >= NN) return;
    int b0 = row_ptr[n];
    int cnt = row_ptr[n + 1] - b0;
    float edn = ed[n];
    float acc[8] = {0.f, 0.f, 0.f, 0.f, 0.f, 0.f, 0.f, 0.f};
    float ws = 0.f;
    int i = 0;
    for (; i + 8 <= cnt; i += 8) {
        int ss[8];
        #pragma unroll
        for (int u = 0; u < 8; ++u) ss[u] = csr[b0 + i + u];
        union { float4 f; __half2 h2[4]; } uu[8];
        #pragma unroll
        for (int u = 0; u < 8; ++u) uu[u].f = *(const float4*)&z2h[(size_t)ss[u] * F2 + j * 8];
        float ww[8];
        #pragma unroll
        for (int u = 0; u < 8; ++u) {
            float e = es[ss[u]] + edn;
            ww[u] = exp2f(e >= 0.f ? e : SLOPE * e);
            ws += ww[u];
        }
        #pragma unroll
        for (int t = 0; t < 4; ++t) {
            #pragma unroll
            for (int u = 0; u < 8; ++u) {
                float2 v = __half22float2(uu[u].h2[t]);
                acc[2*t]   = fmaf(ww[u], v.x, acc[2*t]);
                acc[2*t+1] = fmaf(ww[u], v.y, acc[2*t+1]);
            }
        }
    }
    for (; i < cnt; ++i) {
        int s = csr[b0 + i];
        float e = es[s] + edn;
        float wv = exp2f(e >= 0.f ? e : SLOPE * e);
        ws += wv;
        union { float4 f; __half2 h2[4]; } u;
        u.f = *(const float4*)&z2h[(size_t)s * F2 + j * 8];
        #pragma unroll
        for (int t = 0; t < 4; ++t) {
            float2 v = __half22float2(u.h2[t]);
            acc[2*t]   = fmaf(wv, v.x, acc[2*t]);
            acc[2*t+1] = fmaf(wv, v.y, acc[2*t+1]);
        }
    }
    float rs = ws > 0.f ? 1.0f / ws : 0.f;
    float* op = &out[(size_t)n * F2 + j * 8];
    *(float4*)&op[0] = make_float4(acc[0]*rs, acc[1]*rs, acc[2]*rs, acc[3]*rs);
    *(float4*)&op[4] = make_float4(acc[4]*rs, acc[5]*rs, acc[6]*rs, acc[7]*rs);
}

extern "C" void kernel_launch(void* const* d_in, const int* in_sizes, int n_in,
                              void* d_out, int out_size, void* d_ws, size_t ws_size,
                              hipStream_t stream) {
    const float* h   = (const float*)d_in[0];
    const float* W1  = (const float*)d_in[1];
    const float* a1s = (const float*)d_in[2];
    const float* a1d = (const float*)d_in[3];
    const float* W2  = (const float*)d_in[4];
    const float* a2s = (const float*)d_in[5];
    const float* a2d = (const float*)d_in[6];
    const int*   src = (const int*)d_in[7];
    const int*   dst = (const int*)d_in[8];
    float* out = (float*)d_out;

    // workspace layout (4-byte units, fp regions 16B-aligned)
    int* ip      = (int*)d_ws;
    int* hist    = ip;                       // 512 (zeroed; only [0,BK) used)
    int* cursor  = hist + 512;               // 512 (zeroed)
    int* row_ptr = cursor + 512;             // NN+1 -> pad to NN+8
    unsigned int* sorted = (unsigned int*)(row_ptr + NN + 8);  // EE
    unsigned short* csr16 = (unsigned short*)(sorted + EE);    // EE ushorts
    float* es1x = (float*)(csr16 + EE);      // NN*8
    float* ed1x = es1x + (size_t)NN * NH;    // NN*8
    float* es2x = ed1x + (size_t)NN * NH;    // NN
    float* ed2x = es2x + NN;                 // NN
    __half* z1h = (__half*)(ed2x + NN);      // NN*128
    __half* h1h = z1h + (size_t)NN * F1;     // NN*128
    __half* z2h = h1h + (size_t)NN * F1;     // NN*32
    __half* wt1 = z2h + (size_t)NN * F2;     // 128*128
    __half* wt2 = wt1 + FIN * F1;            // 32*128

    hipMemsetAsync(hist, 0, 1024 * sizeof(int), stream);   // hist + cursor

    k1_hist_prep<<<NBLK + PREPB, 256, 0, stream>>>(dst, W1, W2, wt1, wt2, hist);
    k2_split_gemm1<<<NBLK + GEMM1B, 256, 52224, stream>>>(src, dst, hist, cursor, sorted,
                                                          h, wt1, a1s, a1d, z1h, es1x, ed1x);
    csrbuild_kernel<<<BK, 256, 0, stream>>>(hist, sorted, csr16, row_ptr);
    attn1_kernel<<<(NN * 16 + 255) / 256, 256, 0, stream>>>(row_ptr, csr16, z1h, es1x, ed1x, h1h);
    gemm2_kernel<<<GEMM1B, 256, 0, stream>>>(h1h, wt2, a2s, a2d, z2h, es2x, ed2x);
    attn2_kernel<<<(NN * 4 + 255) / 256, 256, 0, stream>>>(row_ptr, csr16, z2h, es2x, ed2x, out);
}

// Round 12
// 199.370 us; speedup vs baseline: 1.0109x; 1.0109x over previous
//
#include <hip/hip_runtime.h>
#include <hip/hip_fp16.h>
#include <math.h>

#define NN 50000
#define EE 800000
#define FIN 128
#define F1  128   // HEADS*HID
#define NH  8
#define DH  16
#define F2  32
#define SLOPE 0.2f
#define LOG2E 1.44269504f

#define EB 4096                    // edges per split block
#define NBLK ((EE + EB - 1) / EB)  // 196
#define BK  391                    // coarse buckets = ceil(NN/128)
#define SEGCAP 4096                // max edges per bucket segment (mean ~2046)
#define PREPB 80                   // prep blocks: (128*128 + 32*128)/256
#define GEMM1B ((NN + 63) / 64)    // 782

typedef _Float16 f16x8 __attribute__((ext_vector_type(8)));
typedef float    f32x4 __attribute__((ext_vector_type(4)));

// ================= k1: [hist | prep] fused =================
__global__ __launch_bounds__(256) void k1_hist_prep(const int* __restrict__ dst,
        const float* __restrict__ W1, const float* __restrict__ W2,
        __half* __restrict__ wt1, __half* __restrict__ wt2, int* __restrict__ hist) {
    int tid = threadIdx.x;
    if (blockIdx.x < NBLK) {
        __shared__ int lc[BK];
        for (int i = tid; i < BK; i += 256) lc[i] = 0;
        __syncthreads();
        int base = blockIdx.x * EB;
        int end = base + EB; if (end > EE) end = EE;
        for (int i = base + tid; i < end; i += 256)
            atomicAdd(&lc[dst[i] >> 7], 1);
        __syncthreads();
        for (int i = tid; i < BK; i += 256)
            if (lc[i]) atomicAdd(&hist[i], lc[i]);
    } else {
        int gidx = (blockIdx.x - NBLK) * 256 + tid;
        if (gidx < FIN * F1) {
            int n = gidx >> 7, k = gidx & 127;
            wt1[gidx] = __float2half(W1[k * F1 + n]);
        } else {
            int t2 = gidx - FIN * F1;
            if (t2 < F2 * FIN) {
                int n = t2 >> 7, k = t2 & 127;
                wt2[t2] = __float2half(W2[k * F2 + n]);
            }
        }
    }
}

// ================= k2: [split | gemm1] fused (dynamic LDS 52224 B) =================
extern __shared__ char smem_k2[];
__global__ __launch_bounds__(256) void k2_split_gemm1(const int* __restrict__ src,
        const int* __restrict__ dst, const int* __restrict__ hist, int* __restrict__ cursor,
        unsigned int* __restrict__ sorted,
        const float* __restrict__ h, const __half* __restrict__ wt1,
        const float* __restrict__ a1s, const float* __restrict__ a1d,
        __half* __restrict__ z1h, float* __restrict__ es1x, float* __restrict__ ed1x) {
    int tid = threadIdx.x;
    if (blockIdx.x < NBLK) {
        unsigned int*   recs = (unsigned int*)smem_k2;              // 16384 B
        unsigned short* rbk  = (unsigned short*)(smem_k2 + 16384);  // 8192 B
        int* lc    = (int*)(smem_k2 + 24576);                       // 2048 B
        int* lofs  = (int*)(smem_k2 + 26624);                       // 2048 B
        int* lcur  = (int*)(smem_k2 + 28672);                       // 2048 B
        int* delta = (int*)(smem_k2 + 30720);                       // 2048 B
        int* bscan = (int*)(smem_k2 + 32768);                       // 2048 B
        int* sh    = (int*)(smem_k2 + 34816);                       // 1024 B
        for (int i = tid; i < 512; i += 256) lc[i] = 0;
        __syncthreads();
        int base = blockIdx.x * EB;
        int cnt = EE - base; if (cnt > EB) cnt = EB;
        unsigned int myrec[16];
        #pragma unroll
        for (int k = 0; k < 16; ++k) {
            int i = base + tid + k * 256;
            myrec[k] = 0xFFFFFFFFu;
            if (i - base < cnt) {
                unsigned int d = (unsigned int)dst[i];
                myrec[k] = (d << 16) | (unsigned int)src[i];
                atomicAdd(&lc[d >> 7], 1);
            }
        }
        __syncthreads();
        int a0 = lc[2 * tid], a1 = lc[2 * tid + 1];
        int tsum = a0 + a1;
        sh[tid] = tsum;
        __syncthreads();
        for (int off = 1; off < 256; off <<= 1) {
            int t = (tid >= off) ? sh[tid - off] : 0;
            __syncthreads(); sh[tid] += t; __syncthreads();
        }
        int ex = sh[tid] - tsum;
        lofs[2 * tid] = ex;
        lofs[2 * tid + 1] = ex + a0;
        __syncthreads();
        int h0 = hist[2 * tid], h1 = hist[2 * tid + 1];
        int hsum = h0 + h1;
        sh[tid] = hsum;
        __syncthreads();
        for (int off = 1; off < 256; off <<= 1) {
            int t = (tid >= off) ? sh[tid - off] : 0;
            __syncthreads(); sh[tid] += t; __syncthreads();
        }
        int hex = sh[tid] - hsum;
        bscan[2 * tid] = hex;
        bscan[2 * tid + 1] = hex + h0;
        __syncthreads();
        for (int b = tid; b < BK; b += 256) {
            int c = lc[b];
            lcur[b] = lofs[b];
            if (c) {
                int g = atomicAdd(&cursor[b], c);    // cursor zero-initialized
                delta[b] = bscan[b] + g - lofs[b];
            }
        }
        __syncthreads();
        #pragma unroll
        for (int k = 0; k < 16; ++k) {
            if (myrec[k] != 0xFFFFFFFFu) {
                int b = (int)(myrec[k] >> 23);      // dst >> 7
                int pos = atomicAdd(&lcur[b], 1);
                recs[pos] = myrec[k];
                rbk[pos] = (unsigned short)b;
            }
        }
        __syncthreads();
        for (int s = tid; s < cnt; s += 256)
            sorted[s + delta[rbk[s]]] = recs[s];
    } else {
        __half* hs  = (__half*)smem_k2;              // 64*136 = 17408 B
        __half* wls = (__half*)(smem_k2 + 17408);    // 128*136 = 34816 B
        for (int c = tid; c < 2048; c += 256) {
            int row = c >> 4, ch = c & 15;
            *(float4*)&wls[row * 136 + ch * 8] = *(const float4*)&wt1[row * 128 + ch * 8];
        }
        int rowBase = (blockIdx.x - NBLK) * 64;
        for (int idx4 = tid; idx4 < 64 * 32; idx4 += 256) {
            int r = idx4 >> 5, cc = (idx4 & 31) * 4;
            int n = rowBase + r;
            float4 v = (n < NN) ? *(const float4*)&h[(size_t)n * FIN + cc] : make_float4(0, 0, 0, 0);
            union { __half2 h2[2]; int2 i; } u;
            u.h2[0] = __floats2half2_rn(v.x, v.y);
            u.h2[1] = __floats2half2_rn(v.z, v.w);
            *(int2*)&hs[r * 136 + cc] = u.i;
        }
        __syncthreads();
        int l = tid & 63, w = tid >> 6;
        int q = l >> 4, cl = l & 15;
        int m0 = w * 16;
        float as[8], ad[8];
        #pragma unroll
        for (int t = 0; t < 8; ++t) { as[t] = a1s[t * DH + cl]; ad[t] = a1d[t * DH + cl]; }
        f32x4 acc[8];
        #pragma unroll
        for (int t = 0; t < 8; ++t) acc[t] = (f32x4){0.f, 0.f, 0.f, 0.f};
        const __half* ap = &hs[(m0 + cl) * 136 + q * 8];
        const __half* bp = &wls[cl * 136 + q * 8];
        #pragma unroll
        for (int k0 = 0; k0 < 128; k0 += 32) {
            f16x8 af = *(const f16x8*)(ap + k0);
            #pragma unroll
            for (int t = 0; t < 8; ++t) {
                f16x8 bf = *(const f16x8*)(bp + t * 16 * 136 + k0);
                acc[t] = __builtin_amdgcn_mfma_f32_16x16x32_f16(af, bf, acc[t], 0, 0, 0);
            }
        }
        #pragma unroll
        for (int t = 0; t < 8; ++t) {
            #pragma unroll
            for (int reg = 0; reg < 4; ++reg) {
                int row = rowBase + m0 + q * 4 + reg;
                float z = acc[t][reg];
                float s = z * as[t], d = z * ad[t];
                s += __shfl_xor(s, 1, 64); d += __shfl_xor(d, 1, 64);
                s += __shfl_xor(s, 2, 64); d += __shfl_xor(d, 2, 64);
                s += __shfl_xor(s, 4, 64); d += __shfl_xor(d, 4, 64);
                s += __shfl_xor(s, 8, 64); d += __shfl_xor(d, 8, 64);
                if (row < NN) {
                    z1h[(size_t)row * F1 + t * 16 + cl] = __float2half(z);
                    if (cl == 0) {
                        es1x[row * NH + t] = s * LOG2E;
                        ed1x[row * NH + t] = d * LOG2E;
                    }
                }
            }
        }
    }
}

// ================= S4: per-bucket dense CSR build (local hist scan) =================
__global__ __launch_bounds__(256) void csrbuild_kernel(const int* __restrict__ hist,
        const unsigned int* __restrict__ sorted, unsigned short* __restrict__ csr,
        int* __restrict__ row_ptr) {
    __shared__ unsigned int recs[SEGCAP];     // 16 KB
    __shared__ unsigned short csr_sh[SEGCAP]; // 8 KB
    __shared__ int ncnt[128], ncur[128];
    __shared__ int sh[256];
    __shared__ int bscan[512];
    int b = blockIdx.x;
    int tid = threadIdx.x;
    int h0 = hist[2 * tid], h1 = hist[2 * tid + 1];
    int hsum = h0 + h1;
    sh[tid] = hsum;
    if (tid < 128) ncnt[tid] = 0;
    __syncthreads();
    for (int off = 1; off < 256; off <<= 1) {
        int t = (tid >= off) ? sh[tid - off] : 0;
        __syncthreads(); sh[tid] += t; __syncthreads();
    }
    int hex = sh[tid] - hsum;
    bscan[2 * tid] = hex;
    bscan[2 * tid + 1] = hex + h0;
    __syncthreads();
    int s0 = bscan[b], s1 = bscan[b + 1];
    int cnt = s1 - s0; if (cnt > SEGCAP) cnt = SEGCAP;
    for (int i = tid; i < cnt; i += 256) {
        unsigned int r = sorted[s0 + i];
        recs[i] = r;
        atomicAdd(&ncnt[(r >> 16) & 127], 1);
    }
    __syncthreads();
    int v = (tid < 128) ? ncnt[tid] : 0;
    sh[tid] = v;
    __syncthreads();
    for (int off = 1; off < 256; off <<= 1) {
        int t = (tid >= off) ? sh[tid - off] : 0;
        __syncthreads(); sh[tid] += t; __syncthreads();
    }
    int ex = sh[tid] - v;
    if (tid < 128) {
        ncur[tid] = ex;
        int node = b * 128 + tid;
        if (node < NN) row_ptr[node] = s0 + ex;
    }
    if (b == BK - 1 && tid == 0) row_ptr[NN] = EE;
    __syncthreads();
    for (int i = tid; i < cnt; i += 256) {
        unsigned int r = recs[i];
        int local = (r >> 16) & 127;
        int p = atomicAdd(&ncur[local], 1);
        csr_sh[p] = (unsigned short)(r & 0xFFFFu);
    }
    __syncthreads();
    for (int i = tid; i < cnt; i += 256)
        csr[s0 + i] = csr_sh[i];
}

// ================= GEMM2 (MFMA fp16) + fp32 es/ed epilogue =================
__global__ __launch_bounds__(256) void gemm2_kernel(const __half* __restrict__ h1h,
        const __half* __restrict__ wt2, const float* __restrict__ a2s, const float* __restrict__ a2d,
        __half* __restrict__ z2h, float* __restrict__ es2x, float* __restrict__ ed2x) {
    __shared__ alignas(16) __half hs[64 * 136];    // 17.4 KB
    __shared__ alignas(16) __half wls[32 * 136];   // 8.7 KB
    int tid = threadIdx.x;
    for (int c = tid; c < 512; c += 256) {
        int row = c >> 4, ch = c & 15;
        *(float4*)&wls[row * 136 + ch * 8] = *(const float4*)&wt2[row * 128 + ch * 8];
    }
    int rowBase = blockIdx.x * 64;
    for (int idx8 = tid; idx8 < 64 * 16; idx8 += 256) {
        int r = idx8 >> 4, cc = (idx8 & 15) * 8;
        int n = rowBase + r;
        float4 v = make_float4(0, 0, 0, 0);
        if (n < NN) v = *(const float4*)&h1h[(size_t)n * FIN + cc];
        *(float4*)&hs[r * 136 + cc] = v;
    }
    __syncthreads();
    int l = tid & 63, w = tid >> 6;
    int q = l >> 4, cl = l & 15;
    int m0 = w * 16;
    float as0 = a2s[cl], as1 = a2s[16 + cl];
    float ad0 = a2d[cl], ad1 = a2d[16 + cl];
    f32x4 acc[2];
    acc[0] = (f32x4){0.f, 0.f, 0.f, 0.f};
    acc[1] = (f32x4){0.f, 0.f, 0.f, 0.f};
    const __half* ap = &hs[(m0 + cl) * 136 + q * 8];
    const __half* bp = &wls[cl * 136 + q * 8];
    #pragma unroll
    for (int k0 = 0; k0 < 128; k0 += 32) {
        f16x8 af = *(const f16x8*)(ap + k0);
        #pragma unroll
        for (int t = 0; t < 2; ++t) {
            f16x8 bf = *(const f16x8*)(bp + t * 16 * 136 + k0);
            acc[t] = __builtin_amdgcn_mfma_f32_16x16x32_f16(af, bf, acc[t], 0, 0, 0);
        }
    }
    #pragma unroll
    for (int reg = 0; reg < 4; ++reg) {
        int row = rowBase + m0 + q * 4 + reg;
        float s = acc[0][reg] * as0 + acc[1][reg] * as1;
        float d = acc[0][reg] * ad0 + acc[1][reg] * ad1;
        s += __shfl_xor(s, 1, 64); d += __shfl_xor(d, 1, 64);
        s += __shfl_xor(s, 2, 64); d += __shfl_xor(d, 2, 64);
        s += __shfl_xor(s, 4, 64); d += __shfl_xor(d, 4, 64);
        s += __shfl_xor(s, 8, 64); d += __shfl_xor(d, 8, 64);
        if (row < NN) {
            z2h[(size_t)row * F2 + cl]      = __float2half(acc[0][reg]);
            z2h[(size_t)row * F2 + 16 + cl] = __float2half(acc[1][reg]);
            if (cl == 0) {
                es2x[row] = s * LOG2E;
                ed2x[row] = d * LOG2E;
            }
        }
    }
}

// ================= attention layer 1: 16 lanes/node, 4-wide unrolled =================
// 4-wide is the measured sweet spot: 8-wide raised VGPR 16->52, cut occupancy to
// 32%, and grew FETCH 101->139 MB (L2 thrash). See round-11 post-mortem.
__global__ __launch_bounds__(256) void attn1_kernel(const int* __restrict__ row_ptr,
        const unsigned short* __restrict__ csr, const __half* __restrict__ z1h,
        const float* __restrict__ es, const float* __restrict__ ed,
        __half* __restrict__ h1h) {
    int gt = blockIdx.x * 256 + threadIdx.x;
    int n = gt >> 4;          // node
    int j = gt & 15;          // dim-group lane
    int hl = j >> 1;          // head
    if (n >= NN) return;
    int b0 = row_ptr[n];
    int cnt = row_ptr[n + 1] - b0;
    float edn = ed[n * NH + hl];
    float acc[8] = {0.f, 0.f, 0.f, 0.f, 0.f, 0.f, 0.f, 0.f};
    float ws = 0.f;
    int i = 0;
    for (; i + 4 <= cnt; i += 4) {
        int s0 = csr[b0 + i], s1 = csr[b0 + i + 1], s2 = csr[b0 + i + 2], s3 = csr[b0 + i + 3];
        float e0 = es[s0 * NH + hl] + edn;
        float e1 = es[s1 * NH + hl] + edn;
        float e2 = es[s2 * NH + hl] + edn;
        float e3 = es[s3 * NH + hl] + edn;
        union { float4 f; __half2 h2[4]; } u0, u1, u2, u3;
        u0.f = *(const float4*)&z1h[(size_t)s0 * F1 + j * 8];
        u1.f = *(const float4*)&z1h[(size_t)s1 * F1 + j * 8];
        u2.f = *(const float4*)&z1h[(size_t)s2 * F1 + j * 8];
        u3.f = *(const float4*)&z1h[(size_t)s3 * F1 + j * 8];
        float w0 = exp2f(e0 >= 0.f ? e0 : SLOPE * e0);
        float w1 = exp2f(e1 >= 0.f ? e1 : SLOPE * e1);
        float w2 = exp2f(e2 >= 0.f ? e2 : SLOPE * e2);
        float w3 = exp2f(e3 >= 0.f ? e3 : SLOPE * e3);
        ws += (w0 + w1) + (w2 + w3);
        #pragma unroll
        for (int t = 0; t < 4; ++t) {
            float2 v0 = __half22float2(u0.h2[t]);
            float2 v1 = __half22float2(u1.h2[t]);
            float2 v2 = __half22float2(u2.h2[t]);
            float2 v3 = __half22float2(u3.h2[t]);
            acc[2*t]   = fmaf(w0, v0.x, fmaf(w1, v1.x, fmaf(w2, v2.x, fmaf(w3, v3.x, acc[2*t]))));
            acc[2*t+1] = fmaf(w0, v0.y, fmaf(w1, v1.y, fmaf(w2, v2.y, fmaf(w3, v3.y, acc[2*t+1]))));
        }
    }
    for (; i < cnt; ++i) {
        int s = csr[b0 + i];
        float e = es[s * NH + hl] + edn;
        float wv = exp2f(e >= 0.f ? e : SLOPE * e);
        ws += wv;
        union { float4 f; __half2 h2[4]; } u;
        u.f = *(const float4*)&z1h[(size_t)s * F1 + j * 8];
        #pragma unroll
        for (int t = 0; t < 4; ++t) {
            float2 v = __half22float2(u.h2[t]);
            acc[2*t]   = fmaf(wv, v.x, acc[2*t]);
            acc[2*t+1] = fmaf(wv, v.y, acc[2*t+1]);
        }
    }
    float rs = ws > 0.f ? 1.0f / ws : 0.f;
    union { float4 f; __half2 h2[4]; } p;
    #pragma unroll
    for (int t = 0; t < 4; ++t) {
        float x0 = acc[2*t] * rs, x1 = acc[2*t+1] * rs;
        x0 = x0 > 0.f ? x0 : __expf(x0) - 1.0f;   // ELU
        x1 = x1 > 0.f ? x1 : __expf(x1) - 1.0f;
        p.h2[t] = __floats2half2_rn(x0, x1);
    }
    *(float4*)&h1h[(size_t)n * F1 + j * 8] = p.f;
}

// ================= attention layer 2: 4 lanes/node, 4-wide unrolled =================
__global__ __launch_bounds__(256) void attn2_kernel(const int* __restrict__ row_ptr,
        const unsigned short* __restrict__ csr, const __half* __restrict__ z2h,
        const float* __restrict__ es, const float* __restrict__ ed,
        float* __restrict__ out) {
    int gt = blockIdx.x * 256 + threadIdx.x;
    int n = gt >> 2;          // node
    int j = gt & 3;           // dims [8j, 8j+8)
    if (n >= NN) return;
    int b0 = row_ptr[n];
    int cnt = row_ptr[n + 1] - b0;
    float edn = ed[n];
    float acc[8] = {0.f, 0.f, 0.f, 0.f, 0.f, 0.f, 0.f, 0.f};
    float ws = 0.f;
    int i = 0;
    for (; i + 4 <= cnt; i += 4) {
        int s0 = csr[b0 + i], s1 = csr[b0 + i + 1], s2 = csr[b0 + i + 2], s3 = csr[b0 + i + 3];
        float e0 = es[s0] + edn;
        float e1 = es[s1] + edn;
        float e2 = es[s2] + edn;
        float e3 = es[s3] + edn;
        union { float4 f; __half2 h2[4]; } u0, u1, u2, u3;
        u0.f = *(const float4*)&z2h[(size_t)s0 * F2 + j * 8];
        u1.f = *(const float4*)&z2h[(size_t)s1 * F2 + j * 8];
        u2.f = *(const float4*)&z2h[(size_t)s2 * F2 + j * 8];
        u3.f = *(const float4*)&z2h[(size_t)s3 * F2 + j * 8];
        float w0 = exp2f(e0 >= 0.f ? e0 : SLOPE * e0);
        float w1 = exp2f(e1 >= 0.f ? e1 : SLOPE * e1);
        float w2 = exp2f(e2 >= 0.f ? e2 : SLOPE * e2);
        float w3 = exp2f(e3 >= 0.f ? e3 : SLOPE * e3);
        ws += (w0 + w1) + (w2 + w3);
        #pragma unroll
        for (int t = 0; t < 4; ++t) {
            float2 v0 = __half22float2(u0.h2[t]);
            float2 v1 = __half22float2(u1.h2[t]);
            float2 v2 = __half22float2(u2.h2[t]);
            float2 v3 = __half22float2(u3.h2[t]);
            acc[2*t]   = fmaf(w0, v0.x, fmaf(w1, v1.x, fmaf(w2, v2.x, fmaf(w3, v3.x, acc[2*t]))));
            acc[2*t+1] = fmaf(w0, v0.y, fmaf(w1, v1.y, fmaf(w2, v2.y, fmaf(w3, v3.y, acc[2*t+1]))));
        }
    }
    for (; i < cnt; ++i) {
        int s = csr[b0 + i];
        float e = es[s] + edn;
        float wv = exp2f(e >= 0.f ? e : SLOPE * e);
        ws += wv;
        union { float4 f; __half2 h2[4]; } u;
        u.f = *(const float4*)&z2h[(size_t)s * F2 + j * 8];
        #pragma unroll
        for (int t = 0; t < 4; ++t) {
            float2 v = __half22float2(u.h2[t]);
            acc[2*t]   = fmaf(wv, v.x, acc[2*t]);
            acc[2*t+1] = fmaf(wv, v.y, acc[2*t+1]);
        }
    }
    float rs = ws > 0.f ? 1.0f / ws : 0.f;
    float* op = &out[(size_t)n * F2 + j * 8];
    *(float4*)&op[0] = make_float4(acc[0]*rs, acc[1]*rs, acc[2]*rs, acc[3]*rs);
    *(float4*)&op[4] = make_float4(acc[4]*rs, acc[5]*rs, acc[6]*rs, acc[7]*rs);
}

extern "C" void kernel_launch(void* const* d_in, const int* in_sizes, int n_in,
                              void* d_out, int out_size, void* d_ws, size_t ws_size,
                              hipStream_t stream) {
    const float* h   = (const float*)d_in[0];
    const float* W1  = (const float*)d_in[1];
    const float* a1s = (const float*)d_in[2];
    const float* a1d = (const float*)d_in[3];
    const float* W2  = (const float*)d_in[4];
    const float* a2s = (const float*)d_in[5];
    const float* a2d = (const float*)d_in[6];
    const int*   src = (const int*)d_in[7];
    const int*   dst = (const int*)d_in[8];
    float* out = (float*)d_out;

    // workspace layout (4-byte units, fp regions 16B-aligned)
    int* ip      = (int*)d_ws;
    int* hist    = ip;                       // 512 (zeroed; only [0,BK) used)
    int* cursor  = hist + 512;               // 512 (zeroed)
    int* row_ptr = cursor + 512;             // NN+1 -> pad to NN+8
    unsigned int* sorted = (unsigned int*)(row_ptr + NN + 8);  // EE
    unsigned short* csr16 = (unsigned short*)(sorted + EE);    // EE ushorts
    float* es1x = (float*)(csr16 + EE);      // NN*8
    float* ed1x = es1x + (size_t)NN * NH;    // NN*8
    float* es2x = ed1x + (size_t)NN * NH;    // NN
    float* ed2x = es2x + NN;                 // NN
    __half* z1h = (__half*)(ed2x + NN);      // NN*128
    __half* h1h = z1h + (size_t)NN * F1;     // NN*128
    __half* z2h = h1h + (size_t)NN * F1;     // NN*32
    __half* wt1 = z2h + (size_t)NN * F2;     // 128*128
    __half* wt2 = wt1 + FIN * F1;            // 32*128

    hipMemsetAsync(hist, 0, 1024 * sizeof(int), stream);   // hist + cursor

    k1_hist_prep<<<NBLK + PREPB, 256, 0, stream>>>(dst, W1, W2, wt1, wt2, hist);
    k2_split_gemm1<<<NBLK + GEMM1B, 256, 52224, stream>>>(src, dst, hist, cursor, sorted,
                                                          h, wt1, a1s, a1d, z1h, es1x, ed1x);
    csrbuild_kernel<<<BK, 256, 0, stream>>>(hist, sorted, csr16, row_ptr);
    attn1_kernel<<<(NN * 16 + 255) / 256, 256, 0, stream>>>(row_ptr, csr16, z1h, es1x, ed1x, h1h);
    gemm2_kernel<<<GEMM1B, 256, 0, stream>>>(h1h, wt2, a2s, a2d, z2h, es2x, ed2x);
    attn2_kernel<<<(NN * 4 + 255) / 256, 256, 0, stream>>>(row_ptr, csr16, z2h, es2x, ed2x, out);
}

// Round 13
// 195.998 us; speedup vs baseline: 1.0283x; 1.0172x over previous
//
#include <hip/hip_runtime.h>
#include <hip/hip_fp16.h>
#include <math.h>

#define NN 50000
#define EE 800000
#define FIN 128
#define F1  128   // HEADS*HID
#define NH  8
#define DH  16
#define F2  32
#define SLOPE 0.2f
#define LOG2E 1.44269504f

#define EB 4096                    // edges per split block
#define NBLK ((EE + EB - 1) / EB)  // 196
#define BK  391                    // coarse buckets = ceil(NN/128)
#define SEGCAP 4096                // max edges per bucket segment (mean ~2046)
#define PREPB 80                   // prep blocks: (128*128 + 32*128)/256
#define GEMM1B ((NN + 63) / 64)    // 782

typedef _Float16 f16x8 __attribute__((ext_vector_type(8)));
typedef float    f32x4 __attribute__((ext_vector_type(4)));

// ================= k1: [hist | prep] fused =================
__global__ __launch_bounds__(256) void k1_hist_prep(const int* __restrict__ dst,
        const float* __restrict__ W1, const float* __restrict__ W2,
        __half* __restrict__ wt1, __half* __restrict__ wt2, int* __restrict__ hist) {
    int tid = threadIdx.x;
    if (blockIdx.x < NBLK) {
        __shared__ int lc[BK];
        for (int i = tid; i < BK; i += 256) lc[i] = 0;
        __syncthreads();
        int base = blockIdx.x * EB;
        int end = base + EB; if (end > EE) end = EE;
        for (int i = base + tid; i < end; i += 256)
            atomicAdd(&lc[dst[i] >> 7], 1);
        __syncthreads();
        for (int i = tid; i < BK; i += 256)
            if (lc[i]) atomicAdd(&hist[i], lc[i]);
    } else {
        int gidx = (blockIdx.x - NBLK) * 256 + tid;
        if (gidx < FIN * F1) {
            int n = gidx >> 7, k = gidx & 127;
            wt1[gidx] = __float2half(W1[k * F1 + n]);
        } else {
            int t2 = gidx - FIN * F1;
            if (t2 < F2 * FIN) {
                int n = t2 >> 7, k = t2 & 127;
                wt2[t2] = __float2half(W2[k * F2 + n]);
            }
        }
    }
}

// ================= k2: [split | gemm1] fused (dynamic LDS 52224 B) =================
extern __shared__ char smem_k2[];
__global__ __launch_bounds__(256) void k2_split_gemm1(const int* __restrict__ src,
        const int* __restrict__ dst, const int* __restrict__ hist, int* __restrict__ cursor,
        unsigned int* __restrict__ sorted,
        const float* __restrict__ h, const __half* __restrict__ wt1,
        const float* __restrict__ a1s, const float* __restrict__ a1d,
        __half* __restrict__ z1h, float* __restrict__ es1x, float* __restrict__ ed1x) {
    int tid = threadIdx.x;
    if (blockIdx.x < NBLK) {
        unsigned int*   recs = (unsigned int*)smem_k2;              // 16384 B
        unsigned short* rbk  = (unsigned short*)(smem_k2 + 16384);  // 8192 B
        int* lc    = (int*)(smem_k2 + 24576);                       // 2048 B
        int* lofs  = (int*)(smem_k2 + 26624);                       // 2048 B
        int* lcur  = (int*)(smem_k2 + 28672);                       // 2048 B
        int* delta = (int*)(smem_k2 + 30720);                       // 2048 B
        int* bscan = (int*)(smem_k2 + 32768);                       // 2048 B
        int* sh    = (int*)(smem_k2 + 34816);                       // 1024 B
        for (int i = tid; i < 512; i += 256) lc[i] = 0;
        __syncthreads();
        int base = blockIdx.x * EB;
        int cnt = EE - base; if (cnt > EB) cnt = EB;
        unsigned int myrec[16];
        #pragma unroll
        for (int k = 0; k < 16; ++k) {
            int i = base + tid + k * 256;
            myrec[k] = 0xFFFFFFFFu;
            if (i - base < cnt) {
                unsigned int d = (unsigned int)dst[i];
                myrec[k] = (d << 16) | (unsigned int)src[i];
                atomicAdd(&lc[d >> 7], 1);
            }
        }
        __syncthreads();
        int a0 = lc[2 * tid], a1 = lc[2 * tid + 1];
        int tsum = a0 + a1;
        sh[tid] = tsum;
        __syncthreads();
        for (int off = 1; off < 256; off <<= 1) {
            int t = (tid >= off) ? sh[tid - off] : 0;
            __syncthreads(); sh[tid] += t; __syncthreads();
        }
        int ex = sh[tid] - tsum;
        lofs[2 * tid] = ex;
        lofs[2 * tid + 1] = ex + a0;
        __syncthreads();
        int h0 = hist[2 * tid], h1 = hist[2 * tid + 1];
        int hsum = h0 + h1;
        sh[tid] = hsum;
        __syncthreads();
        for (int off = 1; off < 256; off <<= 1) {
            int t = (tid >= off) ? sh[tid - off] : 0;
            __syncthreads(); sh[tid] += t; __syncthreads();
        }
        int hex = sh[tid] - hsum;
        bscan[2 * tid] = hex;
        bscan[2 * tid + 1] = hex + h0;
        __syncthreads();
        for (int b = tid; b < BK; b += 256) {
            int c = lc[b];
            lcur[b] = lofs[b];
            if (c) {
                int g = atomicAdd(&cursor[b], c);    // cursor zero-initialized
                delta[b] = bscan[b] + g - lofs[b];
            }
        }
        __syncthreads();
        #pragma unroll
        for (int k = 0; k < 16; ++k) {
            if (myrec[k] != 0xFFFFFFFFu) {
                int b = (int)(myrec[k] >> 23);      // dst >> 7
                int pos = atomicAdd(&lcur[b], 1);
                recs[pos] = myrec[k];
                rbk[pos] = (unsigned short)b;
            }
        }
        __syncthreads();
        for (int s = tid; s < cnt; s += 256)
            sorted[s + delta[rbk[s]]] = recs[s];
    } else {
        __half* hs  = (__half*)smem_k2;              // 64*136 = 17408 B
        __half* wls = (__half*)(smem_k2 + 17408);    // 128*136 = 34816 B
        for (int c = tid; c < 2048; c += 256) {
            int row = c >> 4, ch = c & 15;
            *(float4*)&wls[row * 136 + ch * 8] = *(const float4*)&wt1[row * 128 + ch * 8];
        }
        int rowBase = (blockIdx.x - NBLK) * 64;
        for (int idx4 = tid; idx4 < 64 * 32; idx4 += 256) {
            int r = idx4 >> 5, cc = (idx4 & 31) * 4;
            int n = rowBase + r;
            float4 v = (n < NN) ? *(const float4*)&h[(size_t)n * FIN + cc] : make_float4(0, 0, 0, 0);
            union { __half2 h2[2]; int2 i; } u;
            u.h2[0] = __floats2half2_rn(v.x, v.y);
            u.h2[1] = __floats2half2_rn(v.z, v.w);
            *(int2*)&hs[r * 136 + cc] = u.i;
        }
        __syncthreads();
        int l = tid & 63, w = tid >> 6;
        int q = l >> 4, cl = l & 15;
        int m0 = w * 16;
        float as[8], ad[8];
        #pragma unroll
        for (int t = 0; t < 8; ++t) { as[t] = a1s[t * DH + cl]; ad[t] = a1d[t * DH + cl]; }
        f32x4 acc[8];
        #pragma unroll
        for (int t = 0; t < 8; ++t) acc[t] = (f32x4){0.f, 0.f, 0.f, 0.f};
        const __half* ap = &hs[(m0 + cl) * 136 + q * 8];
        const __half* bp = &wls[cl * 136 + q * 8];
        #pragma unroll
        for (int k0 = 0; k0 < 128; k0 += 32) {
            f16x8 af = *(const f16x8*)(ap + k0);
            #pragma unroll
            for (int t = 0; t < 8; ++t) {
                f16x8 bf = *(const f16x8*)(bp + t * 16 * 136 + k0);
                acc[t] = __builtin_amdgcn_mfma_f32_16x16x32_f16(af, bf, acc[t], 0, 0, 0);
            }
        }
        #pragma unroll
        for (int t = 0; t < 8; ++t) {
            #pragma unroll
            for (int reg = 0; reg < 4; ++reg) {
                int row = rowBase + m0 + q * 4 + reg;
                float z = acc[t][reg];
                float s = z * as[t], d = z * ad[t];
                s += __shfl_xor(s, 1, 64); d += __shfl_xor(d, 1, 64);
                s += __shfl_xor(s, 2, 64); d += __shfl_xor(d, 2, 64);
                s += __shfl_xor(s, 4, 64); d += __shfl_xor(d, 4, 64);
                s += __shfl_xor(s, 8, 64); d += __shfl_xor(d, 8, 64);
                if (row < NN) {
                    z1h[(size_t)row * F1 + t * 16 + cl] = __float2half(z);
                    if (cl == 0) {
                        es1x[row * NH + t] = s * LOG2E;
                        ed1x[row * NH + t] = d * LOG2E;
                    }
                }
            }
        }
    }
}

// ================= S4: per-bucket dense CSR build (local hist scan) =================
__global__ __launch_bounds__(256) void csrbuild_kernel(const int* __restrict__ hist,
        const unsigned int* __restrict__ sorted, unsigned short* __restrict__ csr,
        int* __restrict__ row_ptr) {
    __shared__ unsigned int recs[SEGCAP];     // 16 KB
    __shared__ unsigned short csr_sh[SEGCAP]; // 8 KB
    __shared__ int ncnt[128], ncur[128];
    __shared__ int sh[256];
    __shared__ int bscan[512];
    int b = blockIdx.x;
    int tid = threadIdx.x;
    int h0 = hist[2 * tid], h1 = hist[2 * tid + 1];
    int hsum = h0 + h1;
    sh[tid] = hsum;
    if (tid < 128) ncnt[tid] = 0;
    __syncthreads();
    for (int off = 1; off < 256; off <<= 1) {
        int t = (tid >= off) ? sh[tid - off] : 0;
        __syncthreads(); sh[tid] += t; __syncthreads();
    }
    int hex = sh[tid] - hsum;
    bscan[2 * tid] = hex;
    bscan[2 * tid + 1] = hex + h0;
    __syncthreads();
    int s0 = bscan[b], s1 = bscan[b + 1];
    int cnt = s1 - s0; if (cnt > SEGCAP) cnt = SEGCAP;
    for (int i = tid; i < cnt; i += 256) {
        unsigned int r = sorted[s0 + i];
        recs[i] = r;
        atomicAdd(&ncnt[(r >> 16) & 127], 1);
    }
    __syncthreads();
    int v = (tid < 128) ? ncnt[tid] : 0;
    sh[tid] = v;
    __syncthreads();
    for (int off = 1; off < 256; off <<= 1) {
        int t = (tid >= off) ? sh[tid - off] : 0;
        __syncthreads(); sh[tid] += t; __syncthreads();
    }
    int ex = sh[tid] - v;
    if (tid < 128) {
        ncur[tid] = ex;
        int node = b * 128 + tid;
        if (node < NN) row_ptr[node] = s0 + ex;
    }
    if (b == BK - 1 && tid == 0) row_ptr[NN] = EE;
    __syncthreads();
    for (int i = tid; i < cnt; i += 256) {
        unsigned int r = recs[i];
        int local = (r >> 16) & 127;
        int p = atomicAdd(&ncur[local], 1);
        csr_sh[p] = (unsigned short)(r & 0xFFFFu);
    }
    __syncthreads();
    for (int i = tid; i < cnt; i += 256)
        csr[s0 + i] = csr_sh[i];
}

// ================= fused attn1 + gemm2 =================
// Block = 64 dst nodes. Phase 1: 4-wide gather attention (validated structure)
// writes ELU'd h1 fp16 DIRECTLY into the gemm2 LDS tile (no global round-trip).
// Phase 2: gemm2 MFMA + fp32 es2/ed2 epilogue from LDS.
__global__ __launch_bounds__(256) void attn1_gemm2_kernel(const int* __restrict__ row_ptr,
        const unsigned short* __restrict__ csr, const __half* __restrict__ z1h,
        const float* __restrict__ es, const float* __restrict__ ed,
        const __half* __restrict__ wt2, const float* __restrict__ a2s, const float* __restrict__ a2d,
        __half* __restrict__ z2h, float* __restrict__ es2x, float* __restrict__ ed2x) {
    __shared__ alignas(16) __half hs[64 * 136];    // 17.4 KB: h1 tile
    __shared__ alignas(16) __half wls[32 * 136];   // 8.7 KB: W2^T
    int tid = threadIdx.x;
    for (int c = tid; c < 512; c += 256) {
        int row = c >> 4, ch = c & 15;
        *(float4*)&wls[row * 136 + ch * 8] = *(const float4*)&wt2[row * 128 + ch * 8];
    }
    int rowBase = blockIdx.x * 64;
    int j = tid & 15;          // dim-group lane: dims [8j, 8j+8)
    int hl = j >> 1;           // head
    #pragma unroll
    for (int pass = 0; pass < 4; ++pass) {
        int lr = pass * 16 + (tid >> 4);   // local row 0..63
        int n = rowBase + lr;
        union { float4 f; __half2 h2[4]; } p;
        if (n < NN) {
            int b0 = row_ptr[n];
            int cnt = row_ptr[n + 1] - b0;
            float edn = ed[n * NH + hl];
            float acc[8] = {0.f, 0.f, 0.f, 0.f, 0.f, 0.f, 0.f, 0.f};
            float ws = 0.f;
            int i = 0;
            for (; i + 4 <= cnt; i += 4) {
                int s0 = csr[b0 + i], s1 = csr[b0 + i + 1], s2 = csr[b0 + i + 2], s3 = csr[b0 + i + 3];
                float e0 = es[s0 * NH + hl] + edn;
                float e1 = es[s1 * NH + hl] + edn;
                float e2 = es[s2 * NH + hl] + edn;
                float e3 = es[s3 * NH + hl] + edn;
                union { float4 f; __half2 h2[4]; } u0, u1, u2, u3;
                u0.f = *(const float4*)&z1h[(size_t)s0 * F1 + j * 8];
                u1.f = *(const float4*)&z1h[(size_t)s1 * F1 + j * 8];
                u2.f = *(const float4*)&z1h[(size_t)s2 * F1 + j * 8];
                u3.f = *(const float4*)&z1h[(size_t)s3 * F1 + j * 8];
                float w0 = exp2f(e0 >= 0.f ? e0 : SLOPE * e0);
                float w1 = exp2f(e1 >= 0.f ? e1 : SLOPE * e1);
                float w2 = exp2f(e2 >= 0.f ? e2 : SLOPE * e2);
                float w3 = exp2f(e3 >= 0.f ? e3 : SLOPE * e3);
                ws += (w0 + w1) + (w2 + w3);
                #pragma unroll
                for (int t = 0; t < 4; ++t) {
                    float2 v0 = __half22float2(u0.h2[t]);
                    float2 v1 = __half22float2(u1.h2[t]);
                    float2 v2 = __half22float2(u2.h2[t]);
                    float2 v3 = __half22float2(u3.h2[t]);
                    acc[2*t]   = fmaf(w0, v0.x, fmaf(w1, v1.x, fmaf(w2, v2.x, fmaf(w3, v3.x, acc[2*t]))));
                    acc[2*t+1] = fmaf(w0, v0.y, fmaf(w1, v1.y, fmaf(w2, v2.y, fmaf(w3, v3.y, acc[2*t+1]))));
                }
            }
            for (; i < cnt; ++i) {
                int s = csr[b0 + i];
                float e = es[s * NH + hl] + edn;
                float wv = exp2f(e >= 0.f ? e : SLOPE * e);
                ws += wv;
                union { float4 f; __half2 h2[4]; } u;
                u.f = *(const float4*)&z1h[(size_t)s * F1 + j * 8];
                #pragma unroll
                for (int t = 0; t < 4; ++t) {
                    float2 v = __half22float2(u.h2[t]);
                    acc[2*t]   = fmaf(wv, v.x, acc[2*t]);
                    acc[2*t+1] = fmaf(wv, v.y, acc[2*t+1]);
                }
            }
            float rs = ws > 0.f ? 1.0f / ws : 0.f;
            #pragma unroll
            for (int t = 0; t < 4; ++t) {
                float x0 = acc[2*t] * rs, x1 = acc[2*t+1] * rs;
                x0 = x0 > 0.f ? x0 : __expf(x0) - 1.0f;   // ELU
                x1 = x1 > 0.f ? x1 : __expf(x1) - 1.0f;
                p.h2[t] = __floats2half2_rn(x0, x1);
            }
        } else {
            p.f = make_float4(0.f, 0.f, 0.f, 0.f);
        }
        *(float4*)&hs[lr * 136 + j * 8] = p.f;
    }
    __syncthreads();
    // ---- phase 2: gemm2 MFMA from LDS ----
    int l = tid & 63, w = tid >> 6;
    int q = l >> 4, cl = l & 15;
    int m0 = w * 16;
    float as0 = a2s[cl], as1 = a2s[16 + cl];
    float ad0 = a2d[cl], ad1 = a2d[16 + cl];
    f32x4 acc2[2];
    acc2[0] = (f32x4){0.f, 0.f, 0.f, 0.f};
    acc2[1] = (f32x4){0.f, 0.f, 0.f, 0.f};
    const __half* ap = &hs[(m0 + cl) * 136 + q * 8];
    const __half* bp = &wls[cl * 136 + q * 8];
    #pragma unroll
    for (int k0 = 0; k0 < 128; k0 += 32) {
        f16x8 af = *(const f16x8*)(ap + k0);
        #pragma unroll
        for (int t = 0; t < 2; ++t) {
            f16x8 bf = *(const f16x8*)(bp + t * 16 * 136 + k0);
            acc2[t] = __builtin_amdgcn_mfma_f32_16x16x32_f16(af, bf, acc2[t], 0, 0, 0);
        }
    }
    #pragma unroll
    for (int reg = 0; reg < 4; ++reg) {
        int row = rowBase + m0 + q * 4 + reg;
        float s = acc2[0][reg] * as0 + acc2[1][reg] * as1;
        float d = acc2[0][reg] * ad0 + acc2[1][reg] * ad1;
        s += __shfl_xor(s, 1, 64); d += __shfl_xor(d, 1, 64);
        s += __shfl_xor(s, 2, 64); d += __shfl_xor(d, 2, 64);
        s += __shfl_xor(s, 4, 64); d += __shfl_xor(d, 4, 64);
        s += __shfl_xor(s, 8, 64); d += __shfl_xor(d, 8, 64);
        if (row < NN) {
            z2h[(size_t)row * F2 + cl]      = __float2half(acc2[0][reg]);
            z2h[(size_t)row * F2 + 16 + cl] = __float2half(acc2[1][reg]);
            if (cl == 0) {
                es2x[row] = s * LOG2E;
                ed2x[row] = d * LOG2E;
            }
        }
    }
}

// ================= attention layer 2: 4 lanes/node, 4-wide unrolled =================
__global__ __launch_bounds__(256) void attn2_kernel(const int* __restrict__ row_ptr,
        const unsigned short* __restrict__ csr, const __half* __restrict__ z2h,
        const float* __restrict__ es, const float* __restrict__ ed,
        float* __restrict__ out) {
    int gt = blockIdx.x * 256 + threadIdx.x;
    int n = gt >> 2;          // node
    int j = gt & 3;           // dims [8j, 8j+8)
    if (n >= NN) return;
    int b0 = row_ptr[n];
    int cnt = row_ptr[n + 1] - b0;
    float edn = ed[n];
    float acc[8] = {0.f, 0.f, 0.f, 0.f, 0.f, 0.f, 0.f, 0.f};
    float ws = 0.f;
    int i = 0;
    for (; i + 4 <= cnt; i += 4) {
        int s0 = csr[b0 + i], s1 = csr[b0 + i + 1], s2 = csr[b0 + i + 2], s3 = csr[b0 + i + 3];
        float e0 = es[s0] + edn;
        float e1 = es[s1] + edn;
        float e2 = es[s2] + edn;
        float e3 = es[s3] + edn;
        union { float4 f; __half2 h2[4]; } u0, u1, u2, u3;
        u0.f = *(const float4*)&z2h[(size_t)s0 * F2 + j * 8];
        u1.f = *(const float4*)&z2h[(size_t)s1 * F2 + j * 8];
        u2.f = *(const float4*)&z2h[(size_t)s2 * F2 + j * 8];
        u3.f = *(const float4*)&z2h[(size_t)s3 * F2 + j * 8];
        float w0 = exp2f(e0 >= 0.f ? e0 : SLOPE * e0);
        float w1 = exp2f(e1 >= 0.f ? e1 : SLOPE * e1);
        float w2 = exp2f(e2 >= 0.f ? e2 : SLOPE * e2);
        float w3 = exp2f(e3 >= 0.f ? e3 : SLOPE * e3);
        ws += (w0 + w1) + (w2 + w3);
        #pragma unroll
        for (int t = 0; t < 4; ++t) {
            float2 v0 = __half22float2(u0.h2[t]);
            float2 v1 = __half22float2(u1.h2[t]);
            float2 v2 = __half22float2(u2.h2[t]);
            float2 v3 = __half22float2(u3.h2[t]);
            acc[2*t]   = fmaf(w0, v0.x, fmaf(w1, v1.x, fmaf(w2, v2.x, fmaf(w3, v3.x, acc[2*t]))));
            acc[2*t+1] = fmaf(w0, v0.y, fmaf(w1, v1.y, fmaf(w2, v2.y, fmaf(w3, v3.y, acc[2*t+1]))));
        }
    }
    for (; i < cnt; ++i) {
        int s = csr[b0 + i];
        float e = es[s] + edn;
        float wv = exp2f(e >= 0.f ? e : SLOPE * e);
        ws += wv;
        union { float4 f; __half2 h2[4]; } u;
        u.f = *(const float4*)&z2h[(size_t)s * F2 + j * 8];
        #pragma unroll
        for (int t = 0; t < 4; ++t) {
            float2 v = __half22float2(u.h2[t]);
            acc[2*t]   = fmaf(wv, v.x, acc[2*t]);
            acc[2*t+1] = fmaf(wv, v.y, acc[2*t+1]);
        }
    }
    float rs = ws > 0.f ? 1.0f / ws : 0.f;
    float* op = &out[(size_t)n * F2 + j * 8];
    *(float4*)&op[0] = make_float4(acc[0]*rs, acc[1]*rs, acc[2]*rs, acc[3]*rs);
    *(float4*)&op[4] = make_float4(acc[4]*rs, acc[5]*rs, acc[6]*rs, acc[7]*rs);
}

extern "C" void kernel_launch(void* const* d_in, const int* in_sizes, int n_in,
                              void* d_out, int out_size, void* d_ws, size_t ws_size,
                              hipStream_t stream) {
    const float* h   = (const float*)d_in[0];
    const float* W1  = (const float*)d_in[1];
    const float* a1s = (const float*)d_in[2];
    const float* a1d = (const float*)d_in[3];
    const float* W2  = (const float*)d_in[4];
    const float* a2s = (const float*)d_in[5];
    const float* a2d = (const float*)d_in[6];
    const int*   src = (const int*)d_in[7];
    const int*   dst = (const int*)d_in[8];
    float* out = (float*)d_out;

    // workspace layout (4-byte units, fp regions 16B-aligned)
    int* ip      = (int*)d_ws;
    int* hist    = ip;                       // 512 (zeroed; only [0,BK) used)
    int* cursor  = hist + 512;               // 512 (zeroed)
    int* row_ptr = cursor + 512;             // NN+1 -> pad to NN+8
    unsigned int* sorted = (unsigned int*)(row_ptr + NN + 8);  // EE
    unsigned short* csr16 = (unsigned short*)(sorted + EE);    // EE ushorts
    float* es1x = (float*)(csr16 + EE);      // NN*8
    float* ed1x = es1x + (size_t)NN * NH;    // NN*8
    float* es2x = ed1x + (size_t)NN * NH;    // NN
    float* ed2x = es2x + NN;                 // NN
    __half* z1h = (__half*)(ed2x + NN);      // NN*128
    __half* z2h = z1h + (size_t)NN * F1;     // NN*32
    __half* wt1 = z2h + (size_t)NN * F2;     // 128*128
    __half* wt2 = wt1 + FIN * F1;            // 32*128

    hipMemsetAsync(hist, 0, 1024 * sizeof(int), stream);   // hist + cursor

    k1_hist_prep<<<NBLK + PREPB, 256, 0, stream>>>(dst, W1, W2, wt1, wt2, hist);
    k2_split_gemm1<<<NBLK + GEMM1B, 256, 52224, stream>>>(src, dst, hist, cursor, sorted,
                                                          h, wt1, a1s, a1d, z1h, es1x, ed1x);
    csrbuild_kernel<<<BK, 256, 0, stream>>>(hist, sorted, csr16, row_ptr);
    attn1_gemm2_kernel<<<GEMM1B, 256, 0, stream>>>(row_ptr, csr16, z1h, es1x, ed1x,
                                                   wt2, a2s, a2d, z2h, es2x, ed2x);
    attn2_kernel<<<(NN * 4 + 255) / 256, 256, 0, stream>>>(row_ptr, csr16, z2h, es2x, ed2x, out);
}

// Round 14
// 194.566 us; speedup vs baseline: 1.0359x; 1.0074x over previous
//
#include <hip/hip_runtime.h>
#include <hip/hip_fp16.h>
#include <math.h>

#define NN 50000
#define EE 800000
#define FIN 128
#define F1  128   // HEADS*HID
#define NH  8
#define DH  16
#define F2  32
#define SLOPE 0.2f
#define LOG2E 1.44269504f

#define EB 4096                    // edges per split block
#define NBLK ((EE + EB - 1) / EB)  // 196
#define BK  391                    // coarse buckets = ceil(NN/128)
#define SEGCAP 4096                // max edges per bucket segment (mean ~2046)
#define PREPB 80                   // prep blocks: (128*128 + 32*128)/256
#define GEMM1B ((NN + 63) / 64)    // 782

typedef _Float16 f16x8 __attribute__((ext_vector_type(8)));
typedef float    f32x4 __attribute__((ext_vector_type(4)));

// ================= k1: [hist | prep] fused =================
__global__ __launch_bounds__(256) void k1_hist_prep(const int* __restrict__ dst,
        const float* __restrict__ W1, const float* __restrict__ W2,
        __half* __restrict__ wt1, __half* __restrict__ wt2, int* __restrict__ hist) {
    int tid = threadIdx.x;
    if (blockIdx.x < NBLK) {
        __shared__ int lc[BK];
        for (int i = tid; i < BK; i += 256) lc[i] = 0;
        __syncthreads();
        int base = blockIdx.x * EB;
        int end = base + EB; if (end > EE) end = EE;
        for (int i = base + tid; i < end; i += 256)
            atomicAdd(&lc[dst[i] >> 7], 1);
        __syncthreads();
        for (int i = tid; i < BK; i += 256)
            if (lc[i]) atomicAdd(&hist[i], lc[i]);
    } else {
        int gidx = (blockIdx.x - NBLK) * 256 + tid;
        if (gidx < FIN * F1) {
            int n = gidx >> 7, k = gidx & 127;
            wt1[gidx] = __float2half(W1[k * F1 + n]);
        } else {
            int t2 = gidx - FIN * F1;
            if (t2 < F2 * FIN) {
                int n = t2 >> 7, k = t2 & 127;
                wt2[t2] = __float2half(W2[k * F2 + n]);
            }
        }
    }
}

// ================= k2: [split | gemm1] fused (dynamic LDS 52224 B) =================
extern __shared__ char smem_k2[];
__global__ __launch_bounds__(256) void k2_split_gemm1(const int* __restrict__ src,
        const int* __restrict__ dst, const int* __restrict__ hist, int* __restrict__ cursor,
        unsigned int* __restrict__ sorted,
        const float* __restrict__ h, const __half* __restrict__ wt1,
        const float* __restrict__ a1s, const float* __restrict__ a1d,
        __half* __restrict__ z1h, float* __restrict__ es1x, float* __restrict__ ed1x) {
    int tid = threadIdx.x;
    if (blockIdx.x < NBLK) {
        unsigned int*   recs = (unsigned int*)smem_k2;              // 16384 B
        unsigned short* rbk  = (unsigned short*)(smem_k2 + 16384);  // 8192 B
        int* lc    = (int*)(smem_k2 + 24576);                       // 2048 B
        int* lofs  = (int*)(smem_k2 + 26624);                       // 2048 B
        int* lcur  = (int*)(smem_k2 + 28672);                       // 2048 B
        int* delta = (int*)(smem_k2 + 30720);                       // 2048 B
        int* bscan = (int*)(smem_k2 + 32768);                       // 2048 B
        int* sh    = (int*)(smem_k2 + 34816);                       // 1024 B
        for (int i = tid; i < 512; i += 256) lc[i] = 0;
        __syncthreads();
        int base = blockIdx.x * EB;
        int cnt = EE - base; if (cnt > EB) cnt = EB;
        unsigned int myrec[16];
        #pragma unroll
        for (int k = 0; k < 16; ++k) {
            int i = base + tid + k * 256;
            myrec[k] = 0xFFFFFFFFu;
            if (i - base < cnt) {
                unsigned int d = (unsigned int)dst[i];
                myrec[k] = (d << 16) | (unsigned int)src[i];
                atomicAdd(&lc[d >> 7], 1);
            }
        }
        __syncthreads();
        int a0 = lc[2 * tid], a1 = lc[2 * tid + 1];
        int tsum = a0 + a1;
        sh[tid] = tsum;
        __syncthreads();
        for (int off = 1; off < 256; off <<= 1) {
            int t = (tid >= off) ? sh[tid - off] : 0;
            __syncthreads(); sh[tid] += t; __syncthreads();
        }
        int ex = sh[tid] - tsum;
        lofs[2 * tid] = ex;
        lofs[2 * tid + 1] = ex + a0;
        __syncthreads();
        int h0 = hist[2 * tid], h1 = hist[2 * tid + 1];
        int hsum = h0 + h1;
        sh[tid] = hsum;
        __syncthreads();
        for (int off = 1; off < 256; off <<= 1) {
            int t = (tid >= off) ? sh[tid - off] : 0;
            __syncthreads(); sh[tid] += t; __syncthreads();
        }
        int hex = sh[tid] - hsum;
        bscan[2 * tid] = hex;
        bscan[2 * tid + 1] = hex + h0;
        __syncthreads();
        for (int b = tid; b < BK; b += 256) {
            int c = lc[b];
            lcur[b] = lofs[b];
            if (c) {
                int g = atomicAdd(&cursor[b], c);    // cursor zero-initialized
                delta[b] = bscan[b] + g - lofs[b];
            }
        }
        __syncthreads();
        #pragma unroll
        for (int k = 0; k < 16; ++k) {
            if (myrec[k] != 0xFFFFFFFFu) {
                int b = (int)(myrec[k] >> 23);      // dst >> 7
                int pos = atomicAdd(&lcur[b], 1);
                recs[pos] = myrec[k];
                rbk[pos] = (unsigned short)b;
            }
        }
        __syncthreads();
        for (int s = tid; s < cnt; s += 256)
            sorted[s + delta[rbk[s]]] = recs[s];
    } else {
        __half* hs  = (__half*)smem_k2;              // 64*136 = 17408 B
        __half* wls = (__half*)(smem_k2 + 17408);    // 128*136 = 34816 B
        for (int c = tid; c < 2048; c += 256) {
            int row = c >> 4, ch = c & 15;
            *(float4*)&wls[row * 136 + ch * 8] = *(const float4*)&wt1[row * 128 + ch * 8];
        }
        int rowBase = (blockIdx.x - NBLK) * 64;
        for (int idx4 = tid; idx4 < 64 * 32; idx4 += 256) {
            int r = idx4 >> 5, cc = (idx4 & 31) * 4;
            int n = rowBase + r;
            float4 v = (n < NN) ? *(const float4*)&h[(size_t)n * FIN + cc] : make_float4(0, 0, 0, 0);
            union { __half2 h2[2]; int2 i; } u;
            u.h2[0] = __floats2half2_rn(v.x, v.y);
            u.h2[1] = __floats2half2_rn(v.z, v.w);
            *(int2*)&hs[r * 136 + cc] = u.i;
        }
        __syncthreads();
        int l = tid & 63, w = tid >> 6;
        int q = l >> 4, cl = l & 15;
        int m0 = w * 16;
        float as[8], ad[8];
        #pragma unroll
        for (int t = 0; t < 8; ++t) { as[t] = a1s[t * DH + cl]; ad[t] = a1d[t * DH + cl]; }
        f32x4 acc[8];
        #pragma unroll
        for (int t = 0; t < 8; ++t) acc[t] = (f32x4){0.f, 0.f, 0.f, 0.f};
        const __half* ap = &hs[(m0 + cl) * 136 + q * 8];
        const __half* bp = &wls[cl * 136 + q * 8];
        #pragma unroll
        for (int k0 = 0; k0 < 128; k0 += 32) {
            f16x8 af = *(const f16x8*)(ap + k0);
            #pragma unroll
            for (int t = 0; t < 8; ++t) {
                f16x8 bf = *(const f16x8*)(bp + t * 16 * 136 + k0);
                acc[t] = __builtin_amdgcn_mfma_f32_16x16x32_f16(af, bf, acc[t], 0, 0, 0);
            }
        }
        #pragma unroll
        for (int t = 0; t < 8; ++t) {
            #pragma unroll
            for (int reg = 0; reg < 4; ++reg) {
                int row = rowBase + m0 + q * 4 + reg;
                float z = acc[t][reg];
                float s = z * as[t], d = z * ad[t];
                s += __shfl_xor(s, 1, 64); d += __shfl_xor(d, 1, 64);
                s += __shfl_xor(s, 2, 64); d += __shfl_xor(d, 2, 64);
                s += __shfl_xor(s, 4, 64); d += __shfl_xor(d, 4, 64);
                s += __shfl_xor(s, 8, 64); d += __shfl_xor(d, 8, 64);
                if (row < NN) {
                    z1h[(size_t)row * F1 + t * 16 + cl] = __float2half(z);
                    if (cl == 0) {
                        es1x[row * NH + t] = s * LOG2E;
                        ed1x[row * NH + t] = d * LOG2E;
                    }
                }
            }
        }
    }
}

// ================= S4: per-bucket dense CSR build (local hist scan) =================
__global__ __launch_bounds__(256) void csrbuild_kernel(const int* __restrict__ hist,
        const unsigned int* __restrict__ sorted, unsigned short* __restrict__ csr,
        int* __restrict__ row_ptr) {
    __shared__ unsigned int recs[SEGCAP];     // 16 KB
    __shared__ unsigned short csr_sh[SEGCAP]; // 8 KB
    __shared__ int ncnt[128], ncur[128];
    __shared__ int sh[256];
    __shared__ int bscan[512];
    int b = blockIdx.x;
    int tid = threadIdx.x;
    int h0 = hist[2 * tid], h1 = hist[2 * tid + 1];
    int hsum = h0 + h1;
    sh[tid] = hsum;
    if (tid < 128) ncnt[tid] = 0;
    __syncthreads();
    for (int off = 1; off < 256; off <<= 1) {
        int t = (tid >= off) ? sh[tid - off] : 0;
        __syncthreads(); sh[tid] += t; __syncthreads();
    }
    int hex = sh[tid] - hsum;
    bscan[2 * tid] = hex;
    bscan[2 * tid + 1] = hex + h0;
    __syncthreads();
    int s0 = bscan[b], s1 = bscan[b + 1];
    int cnt = s1 - s0; if (cnt > SEGCAP) cnt = SEGCAP;
    for (int i = tid; i < cnt; i += 256) {
        unsigned int r = sorted[s0 + i];
        recs[i] = r;
        atomicAdd(&ncnt[(r >> 16) & 127], 1);
    }
    __syncthreads();
    int v = (tid < 128) ? ncnt[tid] : 0;
    sh[tid] = v;
    __syncthreads();
    for (int off = 1; off < 256; off <<= 1) {
        int t = (tid >= off) ? sh[tid - off] : 0;
        __syncthreads(); sh[tid] += t; __syncthreads();
    }
    int ex = sh[tid] - v;
    if (tid < 128) {
        ncur[tid] = ex;
        int node = b * 128 + tid;
        if (node < NN) row_ptr[node] = s0 + ex;
    }
    if (b == BK - 1 && tid == 0) row_ptr[NN] = EE;
    __syncthreads();
    for (int i = tid; i < cnt; i += 256) {
        unsigned int r = recs[i];
        int local = (r >> 16) & 127;
        int p = atomicAdd(&ncur[local], 1);
        csr_sh[p] = (unsigned short)(r & 0xFFFFu);
    }
    __syncthreads();
    for (int i = tid; i < cnt; i += 256)
        csr[s0 + i] = csr_sh[i];
}

// ================= fused attn1 + gemm2, per-wave independent =================
// Block = 64 dst nodes; wave w owns rows [16w, 16w+16). Phase 1: wave gathers its
// own 16 nodes into its private LDS region (no cross-wave barrier — removes the
// max-degree-over-64-nodes imbalance coupling measured as 28% occupancy in r13).
// Phase 2: the same wave runs its 16x32 MFMA + es2/ed2 epilogue immediately.
// Only barrier: after the uniform W2 staging.
__global__ __launch_bounds__(256) void attn1_gemm2_kernel(const int* __restrict__ row_ptr,
        const unsigned short* __restrict__ csr, const __half* __restrict__ z1h,
        const float* __restrict__ es, const float* __restrict__ ed,
        const __half* __restrict__ wt2, const float* __restrict__ a2s, const float* __restrict__ a2d,
        __half* __restrict__ z2h, float* __restrict__ es2x, float* __restrict__ ed2x) {
    __shared__ alignas(16) __half hs[64 * 136];    // 17.4 KB: h1 tile (per-wave 16-row regions)
    __shared__ alignas(16) __half wls[32 * 136];   // 8.7 KB: W2^T
    int tid = threadIdx.x;
    for (int c = tid; c < 512; c += 256) {
        int row = c >> 4, ch = c & 15;
        *(float4*)&wls[row * 136 + ch * 8] = *(const float4*)&wt2[row * 128 + ch * 8];
    }
    __syncthreads();               // sole block-wide barrier (uniform W2 staging)
    int rowBase = blockIdx.x * 64;
    int l = tid & 63, w = tid >> 6;
    int j = l & 15;                // dim-group lane: dims [8j, 8j+8)
    int sub = l >> 4;              // 0..3
    int hl = j >> 1;               // head
    #pragma unroll
    for (int pass = 0; pass < 4; ++pass) {
        int lr = w * 16 + pass * 4 + sub;   // local row, within wave's region
        int n = rowBase + lr;
        union { float4 f; __half2 h2[4]; } p;
        if (n < NN) {
            int b0 = row_ptr[n];
            int cnt = row_ptr[n + 1] - b0;
            float edn = ed[n * NH + hl];
            float acc[8] = {0.f, 0.f, 0.f, 0.f, 0.f, 0.f, 0.f, 0.f};
            float ws = 0.f;
            int i = 0;
            for (; i + 4 <= cnt; i += 4) {
                int s0 = csr[b0 + i], s1 = csr[b0 + i + 1], s2 = csr[b0 + i + 2], s3 = csr[b0 + i + 3];
                float e0 = es[s0 * NH + hl] + edn;
                float e1 = es[s1 * NH + hl] + edn;
                float e2 = es[s2 * NH + hl] + edn;
                float e3 = es[s3 * NH + hl] + edn;
                union { float4 f; __half2 h2[4]; } u0, u1, u2, u3;
                u0.f = *(const float4*)&z1h[(size_t)s0 * F1 + j * 8];
                u1.f = *(const float4*)&z1h[(size_t)s1 * F1 + j * 8];
                u2.f = *(const float4*)&z1h[(size_t)s2 * F1 + j * 8];
                u3.f = *(const float4*)&z1h[(size_t)s3 * F1 + j * 8];
                float w0 = exp2f(e0 >= 0.f ? e0 : SLOPE * e0);
                float w1 = exp2f(e1 >= 0.f ? e1 : SLOPE * e1);
                float w2 = exp2f(e2 >= 0.f ? e2 : SLOPE * e2);
                float w3 = exp2f(e3 >= 0.f ? e3 : SLOPE * e3);
                ws += (w0 + w1) + (w2 + w3);
                #pragma unroll
                for (int t = 0; t < 4; ++t) {
                    float2 v0 = __half22float2(u0.h2[t]);
                    float2 v1 = __half22float2(u1.h2[t]);
                    float2 v2 = __half22float2(u2.h2[t]);
                    float2 v3 = __half22float2(u3.h2[t]);
                    acc[2*t]   = fmaf(w0, v0.x, fmaf(w1, v1.x, fmaf(w2, v2.x, fmaf(w3, v3.x, acc[2*t]))));
                    acc[2*t+1] = fmaf(w0, v0.y, fmaf(w1, v1.y, fmaf(w2, v2.y, fmaf(w3, v3.y, acc[2*t+1]))));
                }
            }
            for (; i < cnt; ++i) {
                int s = csr[b0 + i];
                float e = es[s * NH + hl] + edn;
                float wv = exp2f(e >= 0.f ? e : SLOPE * e);
                ws += wv;
                union { float4 f; __half2 h2[4]; } u;
                u.f = *(const float4*)&z1h[(size_t)s * F1 + j * 8];
                #pragma unroll
                for (int t = 0; t < 4; ++t) {
                    float2 v = __half22float2(u.h2[t]);
                    acc[2*t]   = fmaf(wv, v.x, acc[2*t]);
                    acc[2*t+1] = fmaf(wv, v.y, acc[2*t+1]);
                }
            }
            float rs = ws > 0.f ? 1.0f / ws : 0.f;
            #pragma unroll
            for (int t = 0; t < 4; ++t) {
                float x0 = acc[2*t] * rs, x1 = acc[2*t+1] * rs;
                x0 = x0 > 0.f ? x0 : __expf(x0) - 1.0f;   // ELU
                x1 = x1 > 0.f ? x1 : __expf(x1) - 1.0f;
                p.h2[t] = __floats2half2_rn(x0, x1);
            }
        } else {
            p.f = make_float4(0.f, 0.f, 0.f, 0.f);
        }
        *(float4*)&hs[lr * 136 + j * 8] = p.f;
    }
    // ---- phase 2: this wave's 16x32 MFMA from its own LDS rows (no barrier:
    // rows [16w,16w+16) were written exclusively by this wave) ----
    int q = l >> 4, cl = l & 15;
    int m0 = w * 16;
    float as0 = a2s[cl], as1 = a2s[16 + cl];
    float ad0 = a2d[cl], ad1 = a2d[16 + cl];
    f32x4 acc2[2];
    acc2[0] = (f32x4){0.f, 0.f, 0.f, 0.f};
    acc2[1] = (f32x4){0.f, 0.f, 0.f, 0.f};
    const __half* ap = &hs[(m0 + cl) * 136 + q * 8];
    const __half* bp = &wls[cl * 136 + q * 8];
    #pragma unroll
    for (int k0 = 0; k0 < 128; k0 += 32) {
        f16x8 af = *(const f16x8*)(ap + k0);
        #pragma unroll
        for (int t = 0; t < 2; ++t) {
            f16x8 bf = *(const f16x8*)(bp + t * 16 * 136 + k0);
            acc2[t] = __builtin_amdgcn_mfma_f32_16x16x32_f16(af, bf, acc2[t], 0, 0, 0);
        }
    }
    #pragma unroll
    for (int reg = 0; reg < 4; ++reg) {
        int row = rowBase + m0 + q * 4 + reg;
        float s = acc2[0][reg] * as0 + acc2[1][reg] * as1;
        float d = acc2[0][reg] * ad0 + acc2[1][reg] * ad1;
        s += __shfl_xor(s, 1, 64); d += __shfl_xor(d, 1, 64);
        s += __shfl_xor(s, 2, 64); d += __shfl_xor(d, 2, 64);
        s += __shfl_xor(s, 4, 64); d += __shfl_xor(d, 4, 64);
        s += __shfl_xor(s, 8, 64); d += __shfl_xor(d, 8, 64);
        if (row < NN) {
            z2h[(size_t)row * F2 + cl]      = __float2half(acc2[0][reg]);
            z2h[(size_t)row * F2 + 16 + cl] = __float2half(acc2[1][reg]);
            if (cl == 0) {
                es2x[row] = s * LOG2E;
                ed2x[row] = d * LOG2E;
            }
        }
    }
}

// ================= attention layer 2: 4 lanes/node, 4-wide unrolled =================
__global__ __launch_bounds__(256) void attn2_kernel(const int* __restrict__ row_ptr,
        const unsigned short* __restrict__ csr, const __half* __restrict__ z2h,
        const float* __restrict__ es, const float* __restrict__ ed,
        float* __restrict__ out) {
    int gt = blockIdx.x * 256 + threadIdx.x;
    int n = gt >> 2;          // node
    int j = gt & 3;           // dims [8j, 8j+8)
    if (n >= NN) return;
    int b0 = row_ptr[n];
    int cnt = row_ptr[n + 1] - b0;
    float edn = ed[n];
    float acc[8] = {0.f, 0.f, 0.f, 0.f, 0.f, 0.f, 0.f, 0.f};
    float ws = 0.f;
    int i = 0;
    for (; i + 4 <= cnt; i += 4) {
        int s0 = csr[b0 + i], s1 = csr[b0 + i + 1], s2 = csr[b0 + i + 2], s3 = csr[b0 + i + 3];
        float e0 = es[s0] + edn;
        float e1 = es[s1] + edn;
        float e2 = es[s2] + edn;
        float e3 = es[s3] + edn;
        union { float4 f; __half2 h2[4]; } u0, u1, u2, u3;
        u0.f = *(const float4*)&z2h[(size_t)s0 * F2 + j * 8];
        u1.f = *(const float4*)&z2h[(size_t)s1 * F2 + j * 8];
        u2.f = *(const float4*)&z2h[(size_t)s2 * F2 + j * 8];
        u3.f = *(const float4*)&z2h[(size_t)s3 * F2 + j * 8];
        float w0 = exp2f(e0 >= 0.f ? e0 : SLOPE * e0);
        float w1 = exp2f(e1 >= 0.f ? e1 : SLOPE * e1);
        float w2 = exp2f(e2 >= 0.f ? e2 : SLOPE * e2);
        float w3 = exp2f(e3 >= 0.f ? e3 : SLOPE * e3);
        ws += (w0 + w1) + (w2 + w3);
        #pragma unroll
        for (int t = 0; t < 4; ++t) {
            float2 v0 = __half22float2(u0.h2[t]);
            float2 v1 = __half22float2(u1.h2[t]);
            float2 v2 = __half22float2(u2.h2[t]);
            float2 v3 = __half22float2(u3.h2[t]);
            acc[2*t]   = fmaf(w0, v0.x, fmaf(w1, v1.x, fmaf(w2, v2.x, fmaf(w3, v3.x, acc[2*t]))));
            acc[2*t+1] = fmaf(w0, v0.y, fmaf(w1, v1.y, fmaf(w2, v2.y, fmaf(w3, v3.y, acc[2*t+1]))));
        }
    }
    for (; i < cnt; ++i) {
        int s = csr[b0 + i];
        float e = es[s] + edn;
        float wv = exp2f(e >= 0.f ? e : SLOPE * e);
        ws += wv;
        union { float4 f; __half2 h2[4]; } u;
        u.f = *(const float4*)&z2h[(size_t)s * F2 + j * 8];
        #pragma unroll
        for (int t = 0; t < 4; ++t) {
            float2 v = __half22float2(u.h2[t]);
            acc[2*t]   = fmaf(wv, v.x, acc[2*t]);
            acc[2*t+1] = fmaf(wv, v.y, acc[2*t+1]);
        }
    }
    float rs = ws > 0.f ? 1.0f / ws : 0.f;
    float* op = &out[(size_t)n * F2 + j * 8];
    *(float4*)&op[0] = make_float4(acc[0]*rs, acc[1]*rs, acc[2]*rs, acc[3]*rs);
    *(float4*)&op[4] = make_float4(acc[4]*rs, acc[5]*rs, acc[6]*rs, acc[7]*rs);
}

extern "C" void kernel_launch(void* const* d_in, const int* in_sizes, int n_in,
                              void* d_out, int out_size, void* d_ws, size_t ws_size,
                              hipStream_t stream) {
    const float* h   = (const float*)d_in[0];
    const float* W1  = (const float*)d_in[1];
    const float* a1s = (const float*)d_in[2];
    const float* a1d = (const float*)d_in[3];
    const float* W2  = (const float*)d_in[4];
    const float* a2s = (const float*)d_in[5];
    const float* a2d = (const float*)d_in[6];
    const int*   src = (const int*)d_in[7];
    const int*   dst = (const int*)d_in[8];
    float* out = (float*)d_out;

    // workspace layout (4-byte units, fp regions 16B-aligned)
    int* ip      = (int*)d_ws;
    int* hist    = ip;                       // 512 (zeroed; only [0,BK) used)
    int* cursor  = hist + 512;               // 512 (zeroed)
    int* row_ptr = cursor + 512;             // NN+1 -> pad to NN+8
    unsigned int* sorted = (unsigned int*)(row_ptr + NN + 8);  // EE
    unsigned short* csr16 = (unsigned short*)(sorted + EE);    // EE ushorts
    float* es1x = (float*)(csr16 + EE);      // NN*8
    float* ed1x = es1x + (size_t)NN * NH;    // NN*8
    float* es2x = ed1x + (size_t)NN * NH;    // NN
    float* ed2x = es2x + NN;                 // NN
    __half* z1h = (__half*)(ed2x + NN);      // NN*128
    __half* z2h = z1h + (size_t)NN * F1;     // NN*32
    __half* wt1 = z2h + (size_t)NN * F2;     // 128*128
    __half* wt2 = wt1 + FIN * F1;            // 32*128

    hipMemsetAsync(hist, 0, 1024 * sizeof(int), stream);   // hist + cursor

    k1_hist_prep<<<NBLK + PREPB, 256, 0, stream>>>(dst, W1, W2, wt1, wt2, hist);
    k2_split_gemm1<<<NBLK + GEMM1B, 256, 52224, stream>>>(src, dst, hist, cursor, sorted,
                                                          h, wt1, a1s, a1d, z1h, es1x, ed1x);
    csrbuild_kernel<<<BK, 256, 0, stream>>>(hist, sorted, csr16, row_ptr);
    attn1_gemm2_kernel<<<GEMM1B, 256, 0, stream>>>(row_ptr, csr16, z1h, es1x, ed1x,
                                                   wt2, a2s, a2d, z2h, es2x, ed2x);
    attn2_kernel<<<(NN * 4 + 255) / 256, 256, 0, stream>>>(row_ptr, csr16, z2h, es2x, ed2x, out);
}

// Round 15
// 193.428 us; speedup vs baseline: 1.0420x; 1.0059x over previous
//
#include <hip/hip_runtime.h>
#include <hip/hip_fp16.h>
#include <math.h>

#define NN 50000
#define EE 800000
#define FIN 128
#define F1  128   // HEADS*HID
#define NH  8
#define DH  16
#define F2  32
#define SLOPE 0.2f
#define LOG2E 1.44269504f

#define EB 4096                    // edges per split block
#define NBLK ((EE + EB - 1) / EB)  // 196
#define BK  391                    // coarse buckets = ceil(NN/128)
#define SEGCAP 4096                // max edges per bucket segment (mean ~2046)
#define PREPB 80                   // prep blocks: (128*128 + 32*128)/256
#define GEMM1B ((NN + 63) / 64)    // 782

typedef _Float16 f16x8 __attribute__((ext_vector_type(8)));
typedef float    f32x4 __attribute__((ext_vector_type(4)));

// ================= k1: [hist | prep] fused =================
__global__ __launch_bounds__(256) void k1_hist_prep(const int* __restrict__ dst,
        const float* __restrict__ W1, const float* __restrict__ W2,
        __half* __restrict__ wt1, __half* __restrict__ wt2, int* __restrict__ hist) {
    int tid = threadIdx.x;
    if (blockIdx.x < NBLK) {
        __shared__ int lc[BK];
        for (int i = tid; i < BK; i += 256) lc[i] = 0;
        __syncthreads();
        int base = blockIdx.x * EB;
        int end = base + EB; if (end > EE) end = EE;
        for (int i = base + tid; i < end; i += 256)
            atomicAdd(&lc[dst[i] >> 7], 1);
        __syncthreads();
        for (int i = tid; i < BK; i += 256)
            if (lc[i]) atomicAdd(&hist[i], lc[i]);
    } else {
        int gidx = (blockIdx.x - NBLK) * 256 + tid;
        if (gidx < FIN * F1) {
            int n = gidx >> 7, k = gidx & 127;
            wt1[gidx] = __float2half(W1[k * F1 + n]);
        } else {
            int t2 = gidx - FIN * F1;
            if (t2 < F2 * FIN) {
                int n = t2 >> 7, k = t2 & 127;
                wt2[t2] = __float2half(W2[k * F2 + n]);
            }
        }
    }
}

// ================= k2: [split | gemm1] fused (dynamic LDS 52224 B) =================
extern __shared__ char smem_k2[];
__global__ __launch_bounds__(256) void k2_split_gemm1(const int* __restrict__ src,
        const int* __restrict__ dst, const int* __restrict__ hist, int* __restrict__ cursor,
        unsigned int* __restrict__ sorted,
        const float* __restrict__ h, const __half* __restrict__ wt1,
        const float* __restrict__ a1s, const float* __restrict__ a1d,
        __half* __restrict__ z1h, float* __restrict__ es1x, float* __restrict__ ed1x) {
    int tid = threadIdx.x;
    if (blockIdx.x < NBLK) {
        unsigned int*   recs = (unsigned int*)smem_k2;              // 16384 B
        unsigned short* rbk  = (unsigned short*)(smem_k2 + 16384);  // 8192 B
        int* lc    = (int*)(smem_k2 + 24576);                       // 2048 B
        int* lofs  = (int*)(smem_k2 + 26624);                       // 2048 B
        int* lcur  = (int*)(smem_k2 + 28672);                       // 2048 B
        int* delta = (int*)(smem_k2 + 30720);                       // 2048 B
        int* bscan = (int*)(smem_k2 + 32768);                       // 2048 B
        int* sh    = (int*)(smem_k2 + 34816);                       // 1024 B
        for (int i = tid; i < 512; i += 256) lc[i] = 0;
        __syncthreads();
        int base = blockIdx.x * EB;
        int cnt = EE - base; if (cnt > EB) cnt = EB;
        unsigned int myrec[16];
        #pragma unroll
        for (int k = 0; k < 16; ++k) {
            int i = base + tid + k * 256;
            myrec[k] = 0xFFFFFFFFu;
            if (i - base < cnt) {
                unsigned int d = (unsigned int)dst[i];
                myrec[k] = (d << 16) | (unsigned int)src[i];
                atomicAdd(&lc[d >> 7], 1);
            }
        }
        __syncthreads();
        int a0 = lc[2 * tid], a1 = lc[2 * tid + 1];
        int tsum = a0 + a1;
        sh[tid] = tsum;
        __syncthreads();
        for (int off = 1; off < 256; off <<= 1) {
            int t = (tid >= off) ? sh[tid - off] : 0;
            __syncthreads(); sh[tid] += t; __syncthreads();
        }
        int ex = sh[tid] - tsum;
        lofs[2 * tid] = ex;
        lofs[2 * tid + 1] = ex + a0;
        __syncthreads();
        int h0 = hist[2 * tid], h1 = hist[2 * tid + 1];
        int hsum = h0 + h1;
        sh[tid] = hsum;
        __syncthreads();
        for (int off = 1; off < 256; off <<= 1) {
            int t = (tid >= off) ? sh[tid - off] : 0;
            __syncthreads(); sh[tid] += t; __syncthreads();
        }
        int hex = sh[tid] - hsum;
        bscan[2 * tid] = hex;
        bscan[2 * tid + 1] = hex + h0;
        __syncthreads();
        for (int b = tid; b < BK; b += 256) {
            int c = lc[b];
            lcur[b] = lofs[b];
            if (c) {
                int g = atomicAdd(&cursor[b], c);    // cursor zero-initialized
                delta[b] = bscan[b] + g - lofs[b];
            }
        }
        __syncthreads();
        #pragma unroll
        for (int k = 0; k < 16; ++k) {
            if (myrec[k] != 0xFFFFFFFFu) {
                int b = (int)(myrec[k] >> 23);      // dst >> 7
                int pos = atomicAdd(&lcur[b], 1);
                recs[pos] = myrec[k];
                rbk[pos] = (unsigned short)b;
            }
        }
        __syncthreads();
        for (int s = tid; s < cnt; s += 256)
            sorted[s + delta[rbk[s]]] = recs[s];
    } else {
        __half* hs  = (__half*)smem_k2;              // 64*136 = 17408 B
        __half* wls = (__half*)(smem_k2 + 17408);    // 128*136 = 34816 B
        for (int c = tid; c < 2048; c += 256) {
            int row = c >> 4, ch = c & 15;
            *(float4*)&wls[row * 136 + ch * 8] = *(const float4*)&wt1[row * 128 + ch * 8];
        }
        int rowBase = (blockIdx.x - NBLK) * 64;
        for (int idx4 = tid; idx4 < 64 * 32; idx4 += 256) {
            int r = idx4 >> 5, cc = (idx4 & 31) * 4;
            int n = rowBase + r;
            float4 v = (n < NN) ? *(const float4*)&h[(size_t)n * FIN + cc] : make_float4(0, 0, 0, 0);
            union { __half2 h2[2]; int2 i; } u;
            u.h2[0] = __floats2half2_rn(v.x, v.y);
            u.h2[1] = __floats2half2_rn(v.z, v.w);
            *(int2*)&hs[r * 136 + cc] = u.i;
        }
        __syncthreads();
        int l = tid & 63, w = tid >> 6;
        int q = l >> 4, cl = l & 15;
        int m0 = w * 16;
        float as[8], ad[8];
        #pragma unroll
        for (int t = 0; t < 8; ++t) { as[t] = a1s[t * DH + cl]; ad[t] = a1d[t * DH + cl]; }
        f32x4 acc[8];
        #pragma unroll
        for (int t = 0; t < 8; ++t) acc[t] = (f32x4){0.f, 0.f, 0.f, 0.f};
        const __half* ap = &hs[(m0 + cl) * 136 + q * 8];
        const __half* bp = &wls[cl * 136 + q * 8];
        #pragma unroll
        for (int k0 = 0; k0 < 128; k0 += 32) {
            f16x8 af = *(const f16x8*)(ap + k0);
            #pragma unroll
            for (int t = 0; t < 8; ++t) {
                f16x8 bf = *(const f16x8*)(bp + t * 16 * 136 + k0);
                acc[t] = __builtin_amdgcn_mfma_f32_16x16x32_f16(af, bf, acc[t], 0, 0, 0);
            }
        }
        #pragma unroll
        for (int t = 0; t < 8; ++t) {
            #pragma unroll
            for (int reg = 0; reg < 4; ++reg) {
                int row = rowBase + m0 + q * 4 + reg;
                float z = acc[t][reg];
                float s = z * as[t], d = z * ad[t];
                s += __shfl_xor(s, 1, 64); d += __shfl_xor(d, 1, 64);
                s += __shfl_xor(s, 2, 64); d += __shfl_xor(d, 2, 64);
                s += __shfl_xor(s, 4, 64); d += __shfl_xor(d, 4, 64);
                s += __shfl_xor(s, 8, 64); d += __shfl_xor(d, 8, 64);
                if (row < NN) {
                    z1h[(size_t)row * F1 + t * 16 + cl] = __float2half(z);
                    if (cl == 0) {
                        es1x[row * NH + t] = s * LOG2E;
                        ed1x[row * NH + t] = d * LOG2E;
                    }
                }
            }
        }
    }
}

// ================= S4: per-bucket dense CSR build (local hist scan) =================
__global__ __launch_bounds__(256) void csrbuild_kernel(const int* __restrict__ hist,
        const unsigned int* __restrict__ sorted, unsigned short* __restrict__ csr,
        int* __restrict__ row_ptr) {
    __shared__ unsigned int recs[SEGCAP];     // 16 KB
    __shared__ unsigned short csr_sh[SEGCAP]; // 8 KB
    __shared__ int ncnt[128], ncur[128];
    __shared__ int sh[256];
    __shared__ int bscan[512];
    int b = blockIdx.x;
    int tid = threadIdx.x;
    int h0 = hist[2 * tid], h1 = hist[2 * tid + 1];
    int hsum = h0 + h1;
    sh[tid] = hsum;
    if (tid < 128) ncnt[tid] = 0;
    __syncthreads();
    for (int off = 1; off < 256; off <<= 1) {
        int t = (tid >= off) ? sh[tid - off] : 0;
        __syncthreads(); sh[tid] += t; __syncthreads();
    }
    int hex = sh[tid] - hsum;
    bscan[2 * tid] = hex;
    bscan[2 * tid + 1] = hex + h0;
    __syncthreads();
    int s0 = bscan[b], s1 = bscan[b + 1];
    int cnt = s1 - s0; if (cnt > SEGCAP) cnt = SEGCAP;
    for (int i = tid; i < cnt; i += 256) {
        unsigned int r = sorted[s0 + i];
        recs[i] = r;
        atomicAdd(&ncnt[(r >> 16) & 127], 1);
    }
    __syncthreads();
    int v = (tid < 128) ? ncnt[tid] : 0;
    sh[tid] = v;
    __syncthreads();
    for (int off = 1; off < 256; off <<= 1) {
        int t = (tid >= off) ? sh[tid - off] : 0;
        __syncthreads(); sh[tid] += t; __syncthreads();
    }
    int ex = sh[tid] - v;
    if (tid < 128) {
        ncur[tid] = ex;
        int node = b * 128 + tid;
        if (node < NN) row_ptr[node] = s0 + ex;
    }
    if (b == BK - 1 && tid == 0) row_ptr[NN] = EE;
    __syncthreads();
    for (int i = tid; i < cnt; i += 256) {
        unsigned int r = recs[i];
        int local = (r >> 16) & 127;
        int p = atomicAdd(&ncur[local], 1);
        csr_sh[p] = (unsigned short)(r & 0xFFFFu);
    }
    __syncthreads();
    for (int i = tid; i < cnt; i += 256)
        csr[s0 + i] = csr_sh[i];
}

// ================= fused attn1 + gemm2, 16 nodes/block =================
// Grid = 3125 blocks -> 12500 gather waves (48.8/CU supply; 8 blocks/CU resident).
// Phase 1: each 16-lane group gathers exactly ONE node (no pass loop — this was
// the r13/r14 occupancy limiter: 782-block grid supplied only 12 waves/CU).
// Phase 2: after one barrier, wave 0 alone runs the 16x32 MFMA + epilogue.
__global__ __launch_bounds__(256) void attn1_gemm2_kernel(const int* __restrict__ row_ptr,
        const unsigned short* __restrict__ csr, const __half* __restrict__ z1h,
        const float* __restrict__ es, const float* __restrict__ ed,
        const __half* __restrict__ wt2, const float* __restrict__ a2s, const float* __restrict__ a2d,
        __half* __restrict__ z2h, float* __restrict__ es2x, float* __restrict__ ed2x) {
    __shared__ alignas(16) __half hs[16 * 136];    // 4.3 KB: h1 tile
    __shared__ alignas(16) __half wls[32 * 136];   // 8.7 KB: W2^T
    int tid = threadIdx.x;
    for (int c = tid; c < 512; c += 256) {
        int row = c >> 4, ch = c & 15;
        *(float4*)&wls[row * 136 + ch * 8] = *(const float4*)&wt2[row * 128 + ch * 8];
    }
    int rowBase = blockIdx.x * 16;     // NN % 16 == 0: all rows valid
    int slot = tid >> 4;               // node slot 0..15
    int j = tid & 15;                  // dim-group lane: dims [8j, 8j+8)
    int hl = j >> 1;                   // head
    int n = rowBase + slot;
    union { float4 f; __half2 h2[4]; } p;
    {
        int b0 = row_ptr[n];
        int cnt = row_ptr[n + 1] - b0;
        float edn = ed[n * NH + hl];
        float acc[8] = {0.f, 0.f, 0.f, 0.f, 0.f, 0.f, 0.f, 0.f};
        float ws = 0.f;
        int i = 0;
        for (; i + 4 <= cnt; i += 4) {
            int s0 = csr[b0 + i], s1 = csr[b0 + i + 1], s2 = csr[b0 + i + 2], s3 = csr[b0 + i + 3];
            float e0 = es[s0 * NH + hl] + edn;
            float e1 = es[s1 * NH + hl] + edn;
            float e2 = es[s2 * NH + hl] + edn;
            float e3 = es[s3 * NH + hl] + edn;
            union { float4 f; __half2 h2[4]; } u0, u1, u2, u3;
            u0.f = *(const float4*)&z1h[(size_t)s0 * F1 + j * 8];
            u1.f = *(const float4*)&z1h[(size_t)s1 * F1 + j * 8];
            u2.f = *(const float4*)&z1h[(size_t)s2 * F1 + j * 8];
            u3.f = *(const float4*)&z1h[(size_t)s3 * F1 + j * 8];
            float w0 = exp2f(e0 >= 0.f ? e0 : SLOPE * e0);
            float w1 = exp2f(e1 >= 0.f ? e1 : SLOPE * e1);
            float w2 = exp2f(e2 >= 0.f ? e2 : SLOPE * e2);
            float w3 = exp2f(e3 >= 0.f ? e3 : SLOPE * e3);
            ws += (w0 + w1) + (w2 + w3);
            #pragma unroll
            for (int t = 0; t < 4; ++t) {
                float2 v0 = __half22float2(u0.h2[t]);
                float2 v1 = __half22float2(u1.h2[t]);
                float2 v2 = __half22float2(u2.h2[t]);
                float2 v3 = __half22float2(u3.h2[t]);
                acc[2*t]   = fmaf(w0, v0.x, fmaf(w1, v1.x, fmaf(w2, v2.x, fmaf(w3, v3.x, acc[2*t]))));
                acc[2*t+1] = fmaf(w0, v0.y, fmaf(w1, v1.y, fmaf(w2, v2.y, fmaf(w3, v3.y, acc[2*t+1]))));
            }
        }
        for (; i < cnt; ++i) {
            int s = csr[b0 + i];
            float e = es[s * NH + hl] + edn;
            float wv = exp2f(e >= 0.f ? e : SLOPE * e);
            ws += wv;
            union { float4 f; __half2 h2[4]; } u;
            u.f = *(const float4*)&z1h[(size_t)s * F1 + j * 8];
            #pragma unroll
            for (int t = 0; t < 4; ++t) {
                float2 v = __half22float2(u.h2[t]);
                acc[2*t]   = fmaf(wv, v.x, acc[2*t]);
                acc[2*t+1] = fmaf(wv, v.y, acc[2*t+1]);
            }
        }
        float rs = ws > 0.f ? 1.0f / ws : 0.f;
        #pragma unroll
        for (int t = 0; t < 4; ++t) {
            float x0 = acc[2*t] * rs, x1 = acc[2*t+1] * rs;
            x0 = x0 > 0.f ? x0 : __expf(x0) - 1.0f;   // ELU
            x1 = x1 > 0.f ? x1 : __expf(x1) - 1.0f;
            p.h2[t] = __floats2half2_rn(x0, x1);
        }
    }
    *(float4*)&hs[slot * 136 + j * 8] = p.f;
    __syncthreads();
    // ---- phase 2: wave 0 runs the single 16x32 MFMA + es2/ed2 epilogue ----
    if (tid < 64) {
        int q = tid >> 4, cl = tid & 15;
        float as0 = a2s[cl], as1 = a2s[16 + cl];
        float ad0 = a2d[cl], ad1 = a2d[16 + cl];
        f32x4 acc2[2];
        acc2[0] = (f32x4){0.f, 0.f, 0.f, 0.f};
        acc2[1] = (f32x4){0.f, 0.f, 0.f, 0.f};
        const __half* ap = &hs[cl * 136 + q * 8];
        const __half* bp = &wls[cl * 136 + q * 8];
        #pragma unroll
        for (int k0 = 0; k0 < 128; k0 += 32) {
            f16x8 af = *(const f16x8*)(ap + k0);
            #pragma unroll
            for (int t = 0; t < 2; ++t) {
                f16x8 bf = *(const f16x8*)(bp + t * 16 * 136 + k0);
                acc2[t] = __builtin_amdgcn_mfma_f32_16x16x32_f16(af, bf, acc2[t], 0, 0, 0);
            }
        }
        #pragma unroll
        for (int reg = 0; reg < 4; ++reg) {
            int row = rowBase + q * 4 + reg;
            float s = acc2[0][reg] * as0 + acc2[1][reg] * as1;
            float d = acc2[0][reg] * ad0 + acc2[1][reg] * ad1;
            s += __shfl_xor(s, 1, 64); d += __shfl_xor(d, 1, 64);
            s += __shfl_xor(s, 2, 64); d += __shfl_xor(d, 2, 64);
            s += __shfl_xor(s, 4, 64); d += __shfl_xor(d, 4, 64);
            s += __shfl_xor(s, 8, 64); d += __shfl_xor(d, 8, 64);
            z2h[(size_t)row * F2 + cl]      = __float2half(acc2[0][reg]);
            z2h[(size_t)row * F2 + 16 + cl] = __float2half(acc2[1][reg]);
            if (cl == 0) {
                es2x[row] = s * LOG2E;
                ed2x[row] = d * LOG2E;
            }
        }
    }
}

// ================= attention layer 2: 8 lanes/node, 4-wide unrolled =================
// 8 lanes/node (float2 loads) doubles the wave pool vs 4 lanes (6250 vs 3128 waves)
// — attn2 had the same grid-supply occupancy cap as the fused kernel.
__global__ __launch_bounds__(256) void attn2_kernel(const int* __restrict__ row_ptr,
        const unsigned short* __restrict__ csr, const __half* __restrict__ z2h,
        const float* __restrict__ es, const float* __restrict__ ed,
        float* __restrict__ out) {
    int gt = blockIdx.x * 256 + threadIdx.x;
    int n = gt >> 3;          // node
    int j = gt & 7;           // dims [4j, 4j+4)
    if (n >= NN) return;
    int b0 = row_ptr[n];
    int cnt = row_ptr[n + 1] - b0;
    float edn = ed[n];
    float acc[4] = {0.f, 0.f, 0.f, 0.f};
    float ws = 0.f;
    int i = 0;
    for (; i + 4 <= cnt; i += 4) {
        int s0 = csr[b0 + i], s1 = csr[b0 + i + 1], s2 = csr[b0 + i + 2], s3 = csr[b0 + i + 3];
        float e0 = es[s0] + edn;
        float e1 = es[s1] + edn;
        float e2 = es[s2] + edn;
        float e3 = es[s3] + edn;
        union { float2 f; __half2 h2[2]; } u0, u1, u2, u3;
        u0.f = *(const float2*)&z2h[(size_t)s0 * F2 + j * 4];
        u1.f = *(const float2*)&z2h[(size_t)s1 * F2 + j * 4];
        u2.f = *(const float2*)&z2h[(size_t)s2 * F2 + j * 4];
        u3.f = *(const float2*)&z2h[(size_t)s3 * F2 + j * 4];
        float w0 = exp2f(e0 >= 0.f ? e0 : SLOPE * e0);
        float w1 = exp2f(e1 >= 0.f ? e1 : SLOPE * e1);
        float w2 = exp2f(e2 >= 0.f ? e2 : SLOPE * e2);
        float w3 = exp2f(e3 >= 0.f ? e3 : SLOPE * e3);
        ws += (w0 + w1) + (w2 + w3);
        #pragma unroll
        for (int t = 0; t < 2; ++t) {
            float2 v0 = __half22float2(u0.h2[t]);
            float2 v1 = __half22float2(u1.h2[t]);
            float2 v2 = __half22float2(u2.h2[t]);
            float2 v3 = __half22float2(u3.h2[t]);
            acc[2*t]   = fmaf(w0, v0.x, fmaf(w1, v1.x, fmaf(w2, v2.x, fmaf(w3, v3.x, acc[2*t]))));
            acc[2*t+1] = fmaf(w0, v0.y, fmaf(w1, v1.y, fmaf(w2, v2.y, fmaf(w3, v3.y, acc[2*t+1]))));
        }
    }
    for (; i < cnt; ++i) {
        int s = csr[b0 + i];
        float e = es[s] + edn;
        float wv = exp2f(e >= 0.f ? e : SLOPE * e);
        ws += wv;
        union { float2 f; __half2 h2[2]; } u;
        u.f = *(const float2*)&z2h[(size_t)s * F2 + j * 4];
        #pragma unroll
        for (int t = 0; t < 2; ++t) {
            float2 v = __half22float2(u.h2[t]);
            acc[2*t]   = fmaf(wv, v.x, acc[2*t]);
            acc[2*t+1] = fmaf(wv, v.y, acc[2*t+1]);
        }
    }
    float rs = ws > 0.f ? 1.0f / ws : 0.f;
    *(float4*)&out[(size_t)n * F2 + j * 4] =
        make_float4(acc[0]*rs, acc[1]*rs, acc[2]*rs, acc[3]*rs);
}

extern "C" void kernel_launch(void* const* d_in, const int* in_sizes, int n_in,
                              void* d_out, int out_size, void* d_ws, size_t ws_size,
                              hipStream_t stream) {
    const float* h   = (const float*)d_in[0];
    const float* W1  = (const float*)d_in[1];
    const float* a1s = (const float*)d_in[2];
    const float* a1d = (const float*)d_in[3];
    const float* W2  = (const float*)d_in[4];
    const float* a2s = (const float*)d_in[5];
    const float* a2d = (const float*)d_in[6];
    const int*   src = (const int*)d_in[7];
    const int*   dst = (const int*)d_in[8];
    float* out = (float*)d_out;

    // workspace layout (4-byte units, fp regions 16B-aligned)
    int* ip      = (int*)d_ws;
    int* hist    = ip;                       // 512 (zeroed; only [0,BK) used)
    int* cursor  = hist + 512;               // 512 (zeroed)
    int* row_ptr = cursor + 512;             // NN+1 -> pad to NN+8
    unsigned int* sorted = (unsigned int*)(row_ptr + NN + 8);  // EE
    unsigned short* csr16 = (unsigned short*)(sorted + EE);    // EE ushorts
    float* es1x = (float*)(csr16 + EE);      // NN*8
    float* ed1x = es1x + (size_t)NN * NH;    // NN*8
    float* es2x = ed1x + (size_t)NN * NH;    // NN
    float* ed2x = es2x + NN;                 // NN
    __half* z1h = (__half*)(ed2x + NN);      // NN*128
    __half* z2h = z1h + (size_t)NN * F1;     // NN*32
    __half* wt1 = z2h + (size_t)NN * F2;     // 128*128
    __half* wt2 = wt1 + FIN * F1;            // 32*128

    hipMemsetAsync(hist, 0, 1024 * sizeof(int), stream);   // hist + cursor

    k1_hist_prep<<<NBLK + PREPB, 256, 0, stream>>>(dst, W1, W2, wt1, wt2, hist);
    k2_split_gemm1<<<NBLK + GEMM1B, 256, 52224, stream>>>(src, dst, hist, cursor, sorted,
                                                          h, wt1, a1s, a1d, z1h, es1x, ed1x);
    csrbuild_kernel<<<BK, 256, 0, stream>>>(hist, sorted, csr16, row_ptr);
    attn1_gemm2_kernel<<<(NN / 16), 256, 0, stream>>>(row_ptr, csr16, z1h, es1x, ed1x,
                                                      wt2, a2s, a2d, z2h, es2x, ed2x);
    attn2_kernel<<<(NN * 8 + 255) / 256, 256, 0, stream>>>(row_ptr, csr16, z2h, es2x, ed2x, out);
}